// Round 1
// baseline (1741.397 us; speedup 1.0000x reference)
//
#include <hip/hip_runtime.h>

#define N_NODES 100000
#define E_EDGES 1600000
#define F_IN    128
#define H_DIM   64
#define C_OUT   16
#define L_LAYERS 3

// ---------------- edge-index dtype detection + conversion ----------------
// If edge_index arrived as int64 (little-endian), every odd 32-bit word is 0
// (values < 2^31). If int32, odd words are random src values (P(all 2048
// sampled == 0) ~ 0). detect64 writes flag=1 for int64, 0 for int32.
__global__ void detect64_kernel(const unsigned int* __restrict__ e, int* flag) {
    __shared__ int s_any;
    if (threadIdx.x == 0) s_any = 0;
    __syncthreads();
    int any = 0;
    for (int i = threadIdx.x; i < 2048; i += 256)
        if (e[2 * i + 1] != 0u) any = 1;
    if (any) atomicOr(&s_any, 1);
    __syncthreads();
    if (threadIdx.x == 0) *flag = s_any ? 0 : 1;
}

__global__ void convert_edges_kernel(const void* __restrict__ eidx,
                                     int* __restrict__ e32, const int* __restrict__ flag) {
    int i = blockIdx.x * 256 + threadIdx.x;
    if (i >= 2 * E_EDGES) return;
    int v;
    if (*flag) v = (int)((const long long*)eidx)[i];
    else       v = ((const int*)eidx)[i];
    e32[i] = v;
}

// ---------------- input GEMM: h = leaky_relu(x @ W_in + b_in, 0.01) ----------------
// 16 rows/block, 4 waves, each wave computes 4 rows; lane = output column.
__global__ __launch_bounds__(256) void gemm_in_kernel(
        const float* __restrict__ x, const float* __restrict__ W,
        const float* __restrict__ b, float* __restrict__ h) {
    __shared__ float sW[F_IN * H_DIM];   // 32 KB
    __shared__ float sx[16][F_IN];       // 8 KB
    int t = threadIdx.x;
    for (int i = t; i < F_IN * H_DIM; i += 256) sW[i] = W[i];
    int row0 = blockIdx.x * 16;
    for (int i = t; i < 16 * F_IN; i += 256) {
        int r = i >> 7, k = i & 127;
        sx[r][k] = x[(row0 + r) * F_IN + k];
    }
    __syncthreads();
    int wave = t >> 6, lane = t & 63;
    float bias = b[lane];
    for (int rr = 0; rr < 4; ++rr) {
        int r = wave * 4 + rr;
        float acc = bias;
        #pragma unroll
        for (int k = 0; k < F_IN; ++k) acc += sx[r][k] * sW[k * H_DIM + lane];
        acc = acc > 0.f ? acc : 0.01f * acc;
        h[(row0 + r) * H_DIM + lane] = acc;
    }
}

// ---------------- layer GEMM: hw = h @ Wc ; alpha_s = hw@a_src ; alpha_d = hw@a_dst ----
__global__ __launch_bounds__(256) void gemm_layer_kernel(
        const float* __restrict__ h, const float* __restrict__ Wc,
        const float* __restrict__ asrc, const float* __restrict__ adst,
        float* __restrict__ hw, float* __restrict__ as_, float* __restrict__ ad_) {
    __shared__ float sW[H_DIM * H_DIM];  // 16 KB
    __shared__ float sh[16][H_DIM];      // 4 KB
    int t = threadIdx.x;
    for (int i = t; i < H_DIM * H_DIM; i += 256) sW[i] = Wc[i];
    int row0 = blockIdx.x * 16;
    for (int i = t; i < 16 * H_DIM; i += 256) {
        int r = i >> 6, k = i & 63;
        sh[r][k] = h[(row0 + r) * H_DIM + k];
    }
    __syncthreads();
    int wave = t >> 6, lane = t & 63;
    float aS = asrc[lane], aD = adst[lane];
    for (int rr = 0; rr < 4; ++rr) {
        int r = wave * 4 + rr;
        int row = row0 + r;
        float acc = 0.f;
        #pragma unroll
        for (int k = 0; k < H_DIM; ++k) acc += sh[r][k] * sW[k * H_DIM + lane];
        hw[row * H_DIM + lane] = acc;
        float vs = acc * aS, vd = acc * aD;
        #pragma unroll
        for (int off = 32; off >= 1; off >>= 1) {
            vs += __shfl_xor(vs, off);
            vd += __shfl_xor(vd, off);
        }
        if (lane == 0) { as_[row] = vs; ad_[row] = vd; }
    }
}

// ---------------- edge pass A: ex = exp(leaky(as[src]+ad[dst],0.2)); denom[dst] += ex --
__global__ __launch_bounds__(256) void edge_ex_kernel(
        const int* __restrict__ src, const int* __restrict__ dst,
        const float* __restrict__ as_, const float* __restrict__ ad_,
        float* __restrict__ ex, float* __restrict__ denom) {
    int e = blockIdx.x * 256 + threadIdx.x;
    if (e >= E_EDGES + N_NODES) return;
    int s, d;
    if (e < E_EDGES) { s = src[e]; d = dst[e]; }
    else             { s = d = e - E_EDGES; }
    float v = as_[s] + ad_[d];
    v = v > 0.f ? v : 0.2f * v;
    float p = __expf(v);
    ex[e] = p;
    atomicAdd(&denom[d], p);
}

// ---------------- edge pass B: out[dst,:] += (ex/denom[dst]) * hw[src,:] ----------------
// one wave per edge; lane = feature
__global__ __launch_bounds__(256) void edge_agg_kernel(
        const int* __restrict__ src, const int* __restrict__ dst,
        const float* __restrict__ hw, const float* __restrict__ ex,
        const float* __restrict__ denom, float* __restrict__ out) {
    int widx = (blockIdx.x * 256 + threadIdx.x) >> 6;
    int lane = threadIdx.x & 63;
    if (widx >= E_EDGES + N_NODES) return;
    int s, d;
    if (widx < E_EDGES) { s = src[widx]; d = dst[widx]; }
    else                { s = d = widx - E_EDGES; }
    float w = ex[widx] / (denom[d] + 1e-16f);
    atomicAdd(&out[d * H_DIM + lane], w * hw[s * H_DIM + lane]);
}

// ---------------- bias + activation ----------------
__global__ __launch_bounds__(256) void bias_act_kernel(
        float* __restrict__ h, const float* __restrict__ bc) {
    int i = blockIdx.x * 256 + threadIdx.x;
    if (i >= N_NODES * H_DIM) return;
    float v = h[i] + bc[i & 63];
    h[i] = v > 0.f ? v : 0.01f * v;
}

// ---------------- output GEMM + log_softmax ----------------
// 16 nodes/block; thread (r,c) computes logits[row0+r][c]; reduce within 16-lane groups.
__global__ __launch_bounds__(256) void out_logsoftmax_kernel(
        const float* __restrict__ h, const float* __restrict__ W,
        const float* __restrict__ b, float* __restrict__ out) {
    __shared__ float sW[H_DIM * C_OUT];  // 4 KB
    __shared__ float sh[16][H_DIM];
    __shared__ float sb[C_OUT];
    int t = threadIdx.x;
    for (int i = t; i < H_DIM * C_OUT; i += 256) sW[i] = W[i];
    if (t < C_OUT) sb[t] = b[t];
    int row0 = blockIdx.x * 16;
    for (int i = t; i < 16 * H_DIM; i += 256) {
        int r = i >> 6, k = i & 63;
        sh[r][k] = h[(row0 + r) * H_DIM + k];
    }
    __syncthreads();
    int r = t >> 4, c = t & 15;
    float acc = sb[c];
    #pragma unroll
    for (int k = 0; k < H_DIM; ++k) acc += sh[r][k] * sW[k * C_OUT + c];
    float m = acc;
    #pragma unroll
    for (int off = 8; off >= 1; off >>= 1) m = fmaxf(m, __shfl_xor(m, off, 16));
    float e = __expf(acc - m);
    float ssum = e;
    #pragma unroll
    for (int off = 8; off >= 1; off >>= 1) ssum += __shfl_xor(ssum, off, 16);
    out[(row0 + r) * C_OUT + c] = acc - m - __logf(ssum);
}

extern "C" void kernel_launch(void* const* d_in, const int* in_sizes, int n_in,
                              void* d_out, int out_size, void* d_ws, size_t ws_size,
                              hipStream_t stream) {
    const float* x     = (const float*)d_in[0];
    const void*  eidx  = d_in[1];
    // d_in[2] = edge_weight (unused by reference)
    const float* W_in  = (const float*)d_in[3];
    const float* b_in  = (const float*)d_in[4];
    const float* Wc    = (const float*)d_in[5];
    const float* a_src = (const float*)d_in[6];
    const float* a_dst = (const float*)d_in[7];
    const float* bc    = (const float*)d_in[8];
    const float* W_out = (const float*)d_in[9];
    const float* b_out = (const float*)d_in[10];
    float* out = (float*)d_out;

    // workspace layout
    float* h    = (float*)d_ws;                      // N*64
    float* hw   = h  + (size_t)N_NODES * H_DIM;      // N*64
    float* as_  = hw + (size_t)N_NODES * H_DIM;      // N
    float* ad_  = as_ + N_NODES;                     // N
    float* den  = ad_ + N_NODES;                     // N
    float* ex   = den + N_NODES;                     // E+N
    int*   e32  = (int*)(ex + (E_EDGES + N_NODES));  // 2E
    int*   flag = e32 + 2 * E_EDGES;                 // 1

    detect64_kernel<<<1, 256, 0, stream>>>((const unsigned int*)eidx, flag);
    convert_edges_kernel<<<(2 * E_EDGES + 255) / 256, 256, 0, stream>>>(eidx, e32, flag);
    const int* srcp = e32;
    const int* dstp = e32 + E_EDGES;

    gemm_in_kernel<<<N_NODES / 16, 256, 0, stream>>>(x, W_in, b_in, h);

    int nTot = E_EDGES + N_NODES;
    for (int l = 0; l < L_LAYERS; ++l) {
        gemm_layer_kernel<<<N_NODES / 16, 256, 0, stream>>>(
            h, Wc + l * H_DIM * H_DIM, a_src + l * H_DIM, a_dst + l * H_DIM,
            hw, as_, ad_);
        hipMemsetAsync(den, 0, N_NODES * sizeof(float), stream);
        edge_ex_kernel<<<(nTot + 255) / 256, 256, 0, stream>>>(srcp, dstp, as_, ad_, ex, den);
        hipMemsetAsync(h, 0, (size_t)N_NODES * H_DIM * sizeof(float), stream);
        edge_agg_kernel<<<(nTot * 64 + 255) / 256, 256, 0, stream>>>(srcp, dstp, hw, ex, den, h);
        bias_act_kernel<<<(N_NODES * H_DIM + 255) / 256, 256, 0, stream>>>(h, bc + l * H_DIM);
    }

    out_logsoftmax_kernel<<<N_NODES / 16, 256, 0, stream>>>(h, W_out, b_out, out);
}

// Round 2
// 968.737 us; speedup vs baseline: 1.7976x; 1.7976x over previous
//
#include <hip/hip_runtime.h>

#define N_NODES 100000
#define E_EDGES 1600000
#define F_IN    128
#define H_DIM   64
#define C_OUT   16
#define L_LAYERS 3
#define NTOT    (E_EDGES + N_NODES)
#define MAXD    512   // LDS-staged degree cap; fallback recomputes

// ---------------- edge-index dtype detection + conversion ----------------
__global__ void detect64_kernel(const unsigned int* __restrict__ e, int* flag) {
    __shared__ int s_any;
    if (threadIdx.x == 0) s_any = 0;
    __syncthreads();
    int any = 0;
    for (int i = threadIdx.x; i < 2048; i += 256)
        if (e[2 * i + 1] != 0u) any = 1;
    if (any) atomicOr(&s_any, 1);
    __syncthreads();
    if (threadIdx.x == 0) *flag = s_any ? 0 : 1;
}

__global__ void convert_edges_kernel(const void* __restrict__ eidx,
                                     int* __restrict__ e32, const int* __restrict__ flag) {
    int i = blockIdx.x * 256 + threadIdx.x;
    if (i >= 2 * E_EDGES) return;
    int v;
    if (*flag) v = (int)((const long long*)eidx)[i];
    else       v = ((const int*)eidx)[i];
    e32[i] = v;
}

// ---------------- CSR build: deg -> scan -> scatter ----------------
__global__ void init_deg_kernel(int* __restrict__ deg) {
    int i = blockIdx.x * 256 + threadIdx.x;
    if (i < N_NODES) deg[i] = 1;   // self-loop
}

__global__ void hist_kernel(const int* __restrict__ dst, int* __restrict__ deg) {
    int i = blockIdx.x * 256 + threadIdx.x;
    if (i < E_EDGES) atomicAdd(&deg[dst[i]], 1);
}

// single-block scan over N (1024 threads, CHUNK each)
#define SCAN_T 1024
#define CHUNK  ((N_NODES + SCAN_T - 1) / SCAN_T)
__global__ __launch_bounds__(SCAN_T) void scan_kernel(
        const int* __restrict__ deg, int* __restrict__ row_ptr, int* __restrict__ cur) {
    __shared__ int partial[SCAN_T];
    int t = threadIdx.x;
    int base = t * CHUNK;
    int s = 0;
    for (int j = 0; j < CHUNK; ++j) {
        int idx = base + j;
        if (idx < N_NODES) s += deg[idx];
    }
    partial[t] = s;
    __syncthreads();
    for (int off = 1; off < SCAN_T; off <<= 1) {
        int v = (t >= off) ? partial[t - off] : 0;
        __syncthreads();
        partial[t] += v;
        __syncthreads();
    }
    int running = partial[t] - s;   // exclusive base of this chunk
    for (int j = 0; j < CHUNK; ++j) {
        int idx = base + j;
        if (idx < N_NODES) {
            row_ptr[idx] = running;
            cur[idx] = running;
            running += deg[idx];
        }
    }
    if (t == SCAN_T - 1) row_ptr[N_NODES] = partial[SCAN_T - 1];
}

__global__ void scatter_kernel(const int* __restrict__ src, const int* __restrict__ dst,
                               int* __restrict__ cur, int* __restrict__ csr_src) {
    int i = blockIdx.x * 256 + threadIdx.x;
    if (i >= NTOT) return;
    int s, d;
    if (i < E_EDGES) { s = src[i]; d = dst[i]; }
    else             { s = d = i - E_EDGES; }
    int pos = atomicAdd(&cur[d], 1);
    csr_src[pos] = s;
}

// ---------------- input GEMM: h = leaky_relu(x @ W_in + b_in, 0.01) ----------------
__global__ __launch_bounds__(256) void gemm_in_kernel(
        const float* __restrict__ x, const float* __restrict__ W,
        const float* __restrict__ b, float* __restrict__ h) {
    __shared__ float sW[F_IN * H_DIM];
    __shared__ float sx[16][F_IN];
    int t = threadIdx.x;
    for (int i = t; i < F_IN * H_DIM; i += 256) sW[i] = W[i];
    int row0 = blockIdx.x * 16;
    for (int i = t; i < 16 * F_IN; i += 256) {
        int r = i >> 7, k = i & 127;
        sx[r][k] = x[(row0 + r) * F_IN + k];
    }
    __syncthreads();
    int wave = t >> 6, lane = t & 63;
    float bias = b[lane];
    for (int rr = 0; rr < 4; ++rr) {
        int r = wave * 4 + rr;
        float acc = bias;
        #pragma unroll
        for (int k = 0; k < F_IN; ++k) acc += sx[r][k] * sW[k * H_DIM + lane];
        acc = acc > 0.f ? acc : 0.01f * acc;
        h[(row0 + r) * H_DIM + lane] = acc;
    }
}

// ---------------- layer GEMM: hw = h @ Wc ; alpha contributions ----------------
__global__ __launch_bounds__(256) void gemm_layer_kernel(
        const float* __restrict__ h, const float* __restrict__ Wc,
        const float* __restrict__ asrc, const float* __restrict__ adst,
        float* __restrict__ hw, float* __restrict__ as_, float* __restrict__ ad_) {
    __shared__ float sW[H_DIM * H_DIM];
    __shared__ float sh[16][H_DIM];
    int t = threadIdx.x;
    for (int i = t; i < H_DIM * H_DIM; i += 256) sW[i] = Wc[i];
    int row0 = blockIdx.x * 16;
    for (int i = t; i < 16 * H_DIM; i += 256) {
        int r = i >> 6, k = i & 63;
        sh[r][k] = h[(row0 + r) * H_DIM + k];
    }
    __syncthreads();
    int wave = t >> 6, lane = t & 63;
    float aS = asrc[lane], aD = adst[lane];
    for (int rr = 0; rr < 4; ++rr) {
        int r = wave * 4 + rr;
        int row = row0 + r;
        float acc = 0.f;
        #pragma unroll
        for (int k = 0; k < H_DIM; ++k) acc += sh[r][k] * sW[k * H_DIM + lane];
        hw[row * H_DIM + lane] = acc;
        float vs = acc * aS, vd = acc * aD;
        #pragma unroll
        for (int off = 32; off >= 1; off >>= 1) {
            vs += __shfl_xor(vs, off);
            vd += __shfl_xor(vd, off);
        }
        if (lane == 0) { as_[row] = vs; ad_[row] = vd; }
    }
}

// ---------------- fused aggregation: softmax + weighted gather + bias + act ----
// one wave per dst node; 4 waves / block
__global__ __launch_bounds__(256) void agg_kernel(
        const int* __restrict__ row_ptr, const int* __restrict__ csr_src,
        const float* __restrict__ as_, const float* __restrict__ ad_,
        const float* __restrict__ hw, const float* __restrict__ bc,
        float* __restrict__ hout) {
    __shared__ float exbuf[4][MAXD];
    __shared__ int   sbuf[4][MAXD];
    int wave = threadIdx.x >> 6, lane = threadIdx.x & 63;
    int node = blockIdx.x * 4 + wave;
    if (node >= N_NODES) return;
    int rs = row_ptr[node], re = row_ptr[node + 1];
    int deg = re - rs;
    float aD = ad_[node];
    // phase 1: ex per edge (lane-parallel), stage in LDS, partial denom
    float psum = 0.f;
    for (int i = lane; i < deg; i += 64) {
        int s = csr_src[rs + i];
        float v = as_[s] + aD;
        v = v > 0.f ? v : 0.2f * v;
        float p = __expf(v);
        if (deg <= MAXD) { exbuf[wave][i] = p; sbuf[wave][i] = s; }
        psum += p;
    }
    #pragma unroll
    for (int off = 32; off >= 1; off >>= 1) psum += __shfl_xor(psum, off);
    float inv = 1.f / (psum + 1e-16f);
    // phase 2: weighted accumulation over edges (serial, lanes = features)
    float acc = 0.f;
    if (deg <= MAXD) {
        int i = 0;
        for (; i + 4 <= deg; i += 4) {
            int s0 = sbuf[wave][i],     s1 = sbuf[wave][i + 1];
            int s2 = sbuf[wave][i + 2], s3 = sbuf[wave][i + 3];
            float w0 = exbuf[wave][i]     * inv, w1 = exbuf[wave][i + 1] * inv;
            float w2 = exbuf[wave][i + 2] * inv, w3 = exbuf[wave][i + 3] * inv;
            acc += w0 * hw[(size_t)s0 * H_DIM + lane];
            acc += w1 * hw[(size_t)s1 * H_DIM + lane];
            acc += w2 * hw[(size_t)s2 * H_DIM + lane];
            acc += w3 * hw[(size_t)s3 * H_DIM + lane];
        }
        for (; i < deg; ++i)
            acc += exbuf[wave][i] * inv * hw[(size_t)sbuf[wave][i] * H_DIM + lane];
    } else {
        for (int i = 0; i < deg; ++i) {
            int s = csr_src[rs + i];
            float v = as_[s] + aD;
            v = v > 0.f ? v : 0.2f * v;
            acc += __expf(v) * inv * hw[(size_t)s * H_DIM + lane];
        }
    }
    float v = acc + bc[lane];
    hout[(size_t)node * H_DIM + lane] = v > 0.f ? v : 0.01f * v;
}

// ---------------- output GEMM + log_softmax ----------------
__global__ __launch_bounds__(256) void out_logsoftmax_kernel(
        const float* __restrict__ h, const float* __restrict__ W,
        const float* __restrict__ b, float* __restrict__ out) {
    __shared__ float sW[H_DIM * C_OUT];
    __shared__ float sh[16][H_DIM];
    __shared__ float sb[C_OUT];
    int t = threadIdx.x;
    for (int i = t; i < H_DIM * C_OUT; i += 256) sW[i] = W[i];
    if (t < C_OUT) sb[t] = b[t];
    int row0 = blockIdx.x * 16;
    for (int i = t; i < 16 * H_DIM; i += 256) {
        int r = i >> 6, k = i & 63;
        sh[r][k] = h[(row0 + r) * H_DIM + k];
    }
    __syncthreads();
    int r = t >> 4, c = t & 15;
    float acc = sb[c];
    #pragma unroll
    for (int k = 0; k < H_DIM; ++k) acc += sh[r][k] * sW[k * C_OUT + c];
    float m = acc;
    #pragma unroll
    for (int off = 8; off >= 1; off >>= 1) m = fmaxf(m, __shfl_xor(m, off, 16));
    float e = __expf(acc - m);
    float ssum = e;
    #pragma unroll
    for (int off = 8; off >= 1; off >>= 1) ssum += __shfl_xor(ssum, off, 16);
    out[(row0 + r) * C_OUT + c] = acc - m - __logf(ssum);
}

extern "C" void kernel_launch(void* const* d_in, const int* in_sizes, int n_in,
                              void* d_out, int out_size, void* d_ws, size_t ws_size,
                              hipStream_t stream) {
    const float* x     = (const float*)d_in[0];
    const void*  eidx  = d_in[1];
    const float* W_in  = (const float*)d_in[3];
    const float* b_in  = (const float*)d_in[4];
    const float* Wc    = (const float*)d_in[5];
    const float* a_src = (const float*)d_in[6];
    const float* a_dst = (const float*)d_in[7];
    const float* bc    = (const float*)d_in[8];
    const float* W_out = (const float*)d_in[9];
    const float* b_out = (const float*)d_in[10];
    float* out = (float*)d_out;

    // workspace layout
    float* h       = (float*)d_ws;                       // N*64
    float* hw      = h  + (size_t)N_NODES * H_DIM;       // N*64
    float* as_     = hw + (size_t)N_NODES * H_DIM;       // N
    float* ad_     = as_ + N_NODES;                      // N
    int*   e32     = (int*)(ad_ + N_NODES);              // 2E
    int*   deg     = e32 + 2 * E_EDGES;                  // N
    int*   row_ptr = deg + N_NODES;                      // N+1
    int*   cur     = row_ptr + N_NODES + 1;              // N
    int*   csr_src = cur + N_NODES;                      // E+N
    int*   flag    = csr_src + NTOT;                     // 1

    detect64_kernel<<<1, 256, 0, stream>>>((const unsigned int*)eidx, flag);
    convert_edges_kernel<<<(2 * E_EDGES + 255) / 256, 256, 0, stream>>>(eidx, e32, flag);
    const int* srcp = e32;
    const int* dstp = e32 + E_EDGES;

    // CSR build (by destination), self-loops included
    init_deg_kernel<<<(N_NODES + 255) / 256, 256, 0, stream>>>(deg);
    hist_kernel<<<(E_EDGES + 255) / 256, 256, 0, stream>>>(dstp, deg);
    scan_kernel<<<1, SCAN_T, 0, stream>>>(deg, row_ptr, cur);
    scatter_kernel<<<(NTOT + 255) / 256, 256, 0, stream>>>(srcp, dstp, cur, csr_src);

    gemm_in_kernel<<<N_NODES / 16, 256, 0, stream>>>(x, W_in, b_in, h);

    float* hin = h;
    float* hx  = hw;   // reuse hw buffer alternation not needed; hw holds transformed feats
    for (int l = 0; l < L_LAYERS; ++l) {
        gemm_layer_kernel<<<N_NODES / 16, 256, 0, stream>>>(
            hin, Wc + l * H_DIM * H_DIM, a_src + l * H_DIM, a_dst + l * H_DIM,
            hx, as_, ad_);
        agg_kernel<<<(N_NODES + 3) / 4, 256, 0, stream>>>(
            row_ptr, csr_src, as_, ad_, hx, bc + l * H_DIM, hin);
    }

    out_logsoftmax_kernel<<<N_NODES / 16, 256, 0, stream>>>(hin, W_out, b_out, out);
}

// Round 3
// 723.613 us; speedup vs baseline: 2.4065x; 1.3388x over previous
//
#include <hip/hip_runtime.h>

#define N_NODES 100000
#define E_EDGES 1600000
#define F_IN    128
#define H_DIM   64
#define C_OUT   16
#define L_LAYERS 3
#define NTOT    (E_EDGES + N_NODES)
#define MAXD    512   // LDS-staged degree cap; fallback recomputes

// ---------------- edge-index dtype detection + conversion ----------------
__global__ void detect64_kernel(const unsigned int* __restrict__ e, int* flag) {
    __shared__ int s_any;
    if (threadIdx.x == 0) s_any = 0;
    __syncthreads();
    int any = 0;
    for (int i = threadIdx.x; i < 2048; i += 256)
        if (e[2 * i + 1] != 0u) any = 1;
    if (any) atomicOr(&s_any, 1);
    __syncthreads();
    if (threadIdx.x == 0) *flag = s_any ? 0 : 1;
}

__global__ void convert_edges_kernel(const void* __restrict__ eidx,
                                     int* __restrict__ e32, const int* __restrict__ flag) {
    int i = blockIdx.x * 256 + threadIdx.x;
    if (i >= 2 * E_EDGES) return;
    int v;
    if (*flag) v = (int)((const long long*)eidx)[i];
    else       v = ((const int*)eidx)[i];
    e32[i] = v;
}

// ---------------- CSR build: deg -> 3-phase scan -> scatter ----------------
__global__ void init_deg_kernel(int* __restrict__ deg) {
    int i = blockIdx.x * 256 + threadIdx.x;
    if (i < N_NODES) deg[i] = 1;   // self-loop
}

__global__ void hist_kernel(const int* __restrict__ dst, int* __restrict__ deg) {
    int i = blockIdx.x * 256 + threadIdx.x;
    if (i < E_EDGES) atomicAdd(&deg[dst[i]], 1);
}

#define SCAN_ELEMS 1024
#define SCAN_NB    ((N_NODES + SCAN_ELEMS - 1) / SCAN_ELEMS)   // 98

// phase 1: per-block reduce of 1024 deg entries
__global__ __launch_bounds__(256) void scan_partial_reduce(
        const int* __restrict__ deg, int* __restrict__ partial) {
    __shared__ int sdata[256];
    int b = blockIdx.x, t = threadIdx.x;
    int base = b * SCAN_ELEMS;
    int s = 0;
    #pragma unroll
    for (int j = 0; j < 4; ++j) {
        int idx = base + t + j * 256;
        if (idx < N_NODES) s += deg[idx];
    }
    sdata[t] = s;
    __syncthreads();
    for (int off = 128; off >= 1; off >>= 1) {
        if (t < off) sdata[t] += sdata[t + off];
        __syncthreads();
    }
    if (t == 0) partial[b] = sdata[0];
}

// phase 2: exclusive scan of the SCAN_NB partials (one block), also writes total
__global__ __launch_bounds__(128) void scan_partial_scan(
        int* __restrict__ partial, int* __restrict__ row_ptr) {
    __shared__ int sd[128];
    int t = threadIdx.x;
    int v = (t < SCAN_NB) ? partial[t] : 0;
    sd[t] = v;
    __syncthreads();
    for (int off = 1; off < 128; off <<= 1) {
        int u = (t >= off) ? sd[t - off] : 0;
        __syncthreads();
        sd[t] += u;
        __syncthreads();
    }
    if (t < SCAN_NB) partial[t] = sd[t] - v;          // exclusive
    if (t == 127) row_ptr[N_NODES] = sd[127];          // total = E+N
}

// phase 3: per-block scan of its 1024 elems + offset; writes row_ptr and cur
__global__ __launch_bounds__(256) void scan_write_kernel(
        const int* __restrict__ deg, const int* __restrict__ partial,
        int* __restrict__ row_ptr, int* __restrict__ cur) {
    __shared__ int sd[256];
    int b = blockIdx.x, t = threadIdx.x;
    int base = b * SCAN_ELEMS + t * 4;
    int d0 = 0, d1 = 0, d2 = 0, d3 = 0;
    if (base + 0 < N_NODES) d0 = deg[base + 0];
    if (base + 1 < N_NODES) d1 = deg[base + 1];
    if (base + 2 < N_NODES) d2 = deg[base + 2];
    if (base + 3 < N_NODES) d3 = deg[base + 3];
    int tsum = d0 + d1 + d2 + d3;
    sd[t] = tsum;
    __syncthreads();
    for (int off = 1; off < 256; off <<= 1) {
        int u = (t >= off) ? sd[t - off] : 0;
        __syncthreads();
        sd[t] += u;
        __syncthreads();
    }
    int running = partial[b] + sd[t] - tsum;   // exclusive prefix for this thread
    if (base + 0 < N_NODES) { row_ptr[base + 0] = running; cur[base + 0] = running; running += d0; }
    if (base + 1 < N_NODES) { row_ptr[base + 1] = running; cur[base + 1] = running; running += d1; }
    if (base + 2 < N_NODES) { row_ptr[base + 2] = running; cur[base + 2] = running; running += d2; }
    if (base + 3 < N_NODES) { row_ptr[base + 3] = running; cur[base + 3] = running; running += d3; }
}

__global__ void scatter_kernel(const int* __restrict__ src, const int* __restrict__ dst,
                               int* __restrict__ cur, int* __restrict__ csr_src) {
    int i = blockIdx.x * 256 + threadIdx.x;
    if (i >= NTOT) return;
    int s, d;
    if (i < E_EDGES) { s = src[i]; d = dst[i]; }
    else             { s = d = i - E_EDGES; }
    int pos = atomicAdd(&cur[d], 1);
    csr_src[pos] = s;
}

// ---------------- input GEMM: h = leaky_relu(x @ W_in + b_in, 0.01) ----------------
__global__ __launch_bounds__(256) void gemm_in_kernel(
        const float* __restrict__ x, const float* __restrict__ W,
        const float* __restrict__ b, float* __restrict__ h) {
    __shared__ float sW[F_IN * H_DIM];
    __shared__ float sx[16][F_IN];
    int t = threadIdx.x;
    for (int i = t; i < F_IN * H_DIM; i += 256) sW[i] = W[i];
    int row0 = blockIdx.x * 16;
    for (int i = t; i < 16 * F_IN; i += 256) {
        int r = i >> 7, k = i & 127;
        sx[r][k] = x[(row0 + r) * F_IN + k];
    }
    __syncthreads();
    int wave = t >> 6, lane = t & 63;
    float bias = b[lane];
    for (int rr = 0; rr < 4; ++rr) {
        int r = wave * 4 + rr;
        float acc = bias;
        #pragma unroll
        for (int k = 0; k < F_IN; ++k) acc += sx[r][k] * sW[k * H_DIM + lane];
        acc = acc > 0.f ? acc : 0.01f * acc;
        h[(row0 + r) * H_DIM + lane] = acc;
    }
}

// ---------------- layer GEMM: hw = h @ Wc ; alpha contributions ----------------
__global__ __launch_bounds__(256) void gemm_layer_kernel(
        const float* __restrict__ h, const float* __restrict__ Wc,
        const float* __restrict__ asrc, const float* __restrict__ adst,
        float* __restrict__ hw, float* __restrict__ as_, float* __restrict__ ad_) {
    __shared__ float sW[H_DIM * H_DIM];
    __shared__ float sh[16][H_DIM];
    int t = threadIdx.x;
    for (int i = t; i < H_DIM * H_DIM; i += 256) sW[i] = Wc[i];
    int row0 = blockIdx.x * 16;
    for (int i = t; i < 16 * H_DIM; i += 256) {
        int r = i >> 6, k = i & 63;
        sh[r][k] = h[(row0 + r) * H_DIM + k];
    }
    __syncthreads();
    int wave = t >> 6, lane = t & 63;
    float aS = asrc[lane], aD = adst[lane];
    for (int rr = 0; rr < 4; ++rr) {
        int r = wave * 4 + rr;
        int row = row0 + r;
        float acc = 0.f;
        #pragma unroll
        for (int k = 0; k < H_DIM; ++k) acc += sh[r][k] * sW[k * H_DIM + lane];
        hw[row * H_DIM + lane] = acc;
        float vs = acc * aS, vd = acc * aD;
        #pragma unroll
        for (int off = 32; off >= 1; off >>= 1) {
            vs += __shfl_xor(vs, off);
            vd += __shfl_xor(vd, off);
        }
        if (lane == 0) { as_[row] = vs; ad_[row] = vd; }
    }
}

// ---------------- fused aggregation: softmax + weighted gather + bias + act ----
__global__ __launch_bounds__(256) void agg_kernel(
        const int* __restrict__ row_ptr, const int* __restrict__ csr_src,
        const float* __restrict__ as_, const float* __restrict__ ad_,
        const float* __restrict__ hw, const float* __restrict__ bc,
        float* __restrict__ hout) {
    __shared__ float exbuf[4][MAXD];
    __shared__ int   sbuf[4][MAXD];
    int wave = threadIdx.x >> 6, lane = threadIdx.x & 63;
    int node = blockIdx.x * 4 + wave;
    if (node >= N_NODES) return;
    int rs = row_ptr[node], re = row_ptr[node + 1];
    int deg = re - rs;
    float aD = ad_[node];
    float psum = 0.f;
    for (int i = lane; i < deg; i += 64) {
        int s = csr_src[rs + i];
        float v = as_[s] + aD;
        v = v > 0.f ? v : 0.2f * v;
        float p = __expf(v);
        if (deg <= MAXD) { exbuf[wave][i] = p; sbuf[wave][i] = s; }
        psum += p;
    }
    #pragma unroll
    for (int off = 32; off >= 1; off >>= 1) psum += __shfl_xor(psum, off);
    float inv = 1.f / (psum + 1e-16f);
    float acc = 0.f;
    if (deg <= MAXD) {
        int i = 0;
        for (; i + 4 <= deg; i += 4) {
            int s0 = sbuf[wave][i],     s1 = sbuf[wave][i + 1];
            int s2 = sbuf[wave][i + 2], s3 = sbuf[wave][i + 3];
            float w0 = exbuf[wave][i]     * inv, w1 = exbuf[wave][i + 1] * inv;
            float w2 = exbuf[wave][i + 2] * inv, w3 = exbuf[wave][i + 3] * inv;
            acc += w0 * hw[(size_t)s0 * H_DIM + lane];
            acc += w1 * hw[(size_t)s1 * H_DIM + lane];
            acc += w2 * hw[(size_t)s2 * H_DIM + lane];
            acc += w3 * hw[(size_t)s3 * H_DIM + lane];
        }
        for (; i < deg; ++i)
            acc += exbuf[wave][i] * inv * hw[(size_t)sbuf[wave][i] * H_DIM + lane];
    } else {
        for (int i = 0; i < deg; ++i) {
            int s = csr_src[rs + i];
            float v = as_[s] + aD;
            v = v > 0.f ? v : 0.2f * v;
            acc += __expf(v) * inv * hw[(size_t)s * H_DIM + lane];
        }
    }
    float v = acc + bc[lane];
    hout[(size_t)node * H_DIM + lane] = v > 0.f ? v : 0.01f * v;
}

// ---------------- output GEMM + log_softmax ----------------
__global__ __launch_bounds__(256) void out_logsoftmax_kernel(
        const float* __restrict__ h, const float* __restrict__ W,
        const float* __restrict__ b, float* __restrict__ out) {
    __shared__ float sW[H_DIM * C_OUT];
    __shared__ float sh[16][H_DIM];
    __shared__ float sb[C_OUT];
    int t = threadIdx.x;
    for (int i = t; i < H_DIM * C_OUT; i += 256) sW[i] = W[i];
    if (t < C_OUT) sb[t] = b[t];
    int row0 = blockIdx.x * 16;
    for (int i = t; i < 16 * H_DIM; i += 256) {
        int r = i >> 6, k = i & 63;
        sh[r][k] = h[(row0 + r) * H_DIM + k];
    }
    __syncthreads();
    int r = t >> 4, c = t & 15;
    float acc = sb[c];
    #pragma unroll
    for (int k = 0; k < H_DIM; ++k) acc += sh[r][k] * sW[k * C_OUT + c];
    float m = acc;
    #pragma unroll
    for (int off = 8; off >= 1; off >>= 1) m = fmaxf(m, __shfl_xor(m, off, 16));
    float e = __expf(acc - m);
    float ssum = e;
    #pragma unroll
    for (int off = 8; off >= 1; off >>= 1) ssum += __shfl_xor(ssum, off, 16);
    out[(row0 + r) * C_OUT + c] = acc - m - __logf(ssum);
}

extern "C" void kernel_launch(void* const* d_in, const int* in_sizes, int n_in,
                              void* d_out, int out_size, void* d_ws, size_t ws_size,
                              hipStream_t stream) {
    const float* x     = (const float*)d_in[0];
    const void*  eidx  = d_in[1];
    const float* W_in  = (const float*)d_in[3];
    const float* b_in  = (const float*)d_in[4];
    const float* Wc    = (const float*)d_in[5];
    const float* a_src = (const float*)d_in[6];
    const float* a_dst = (const float*)d_in[7];
    const float* bc    = (const float*)d_in[8];
    const float* W_out = (const float*)d_in[9];
    const float* b_out = (const float*)d_in[10];
    float* out = (float*)d_out;

    // workspace layout
    float* h       = (float*)d_ws;                       // N*64
    float* hw      = h  + (size_t)N_NODES * H_DIM;       // N*64
    float* as_     = hw + (size_t)N_NODES * H_DIM;       // N
    float* ad_     = as_ + N_NODES;                      // N
    int*   e32     = (int*)(ad_ + N_NODES);              // 2E
    int*   deg     = e32 + 2 * E_EDGES;                  // N
    int*   row_ptr = deg + N_NODES;                      // N+1
    int*   cur     = row_ptr + N_NODES + 1;              // N
    int*   csr_src = cur + N_NODES;                      // E+N
    int*   partial = csr_src + NTOT;                     // SCAN_NB
    int*   flag    = partial + SCAN_NB;                  // 1

    detect64_kernel<<<1, 256, 0, stream>>>((const unsigned int*)eidx, flag);
    convert_edges_kernel<<<(2 * E_EDGES + 255) / 256, 256, 0, stream>>>(eidx, e32, flag);
    const int* srcp = e32;
    const int* dstp = e32 + E_EDGES;

    // CSR build (by destination), self-loops included
    init_deg_kernel<<<(N_NODES + 255) / 256, 256, 0, stream>>>(deg);
    hist_kernel<<<(E_EDGES + 255) / 256, 256, 0, stream>>>(dstp, deg);
    scan_partial_reduce<<<SCAN_NB, 256, 0, stream>>>(deg, partial);
    scan_partial_scan<<<1, 128, 0, stream>>>(partial, row_ptr);
    scan_write_kernel<<<SCAN_NB, 256, 0, stream>>>(deg, partial, row_ptr, cur);
    scatter_kernel<<<(NTOT + 255) / 256, 256, 0, stream>>>(srcp, dstp, cur, csr_src);

    gemm_in_kernel<<<N_NODES / 16, 256, 0, stream>>>(x, W_in, b_in, h);

    float* hin = h;
    float* hx  = hw;
    for (int l = 0; l < L_LAYERS; ++l) {
        gemm_layer_kernel<<<N_NODES / 16, 256, 0, stream>>>(
            hin, Wc + l * H_DIM * H_DIM, a_src + l * H_DIM, a_dst + l * H_DIM,
            hx, as_, ad_);
        agg_kernel<<<(N_NODES + 3) / 4, 256, 0, stream>>>(
            row_ptr, csr_src, as_, ad_, hx, bc + l * H_DIM, hin);
    }

    out_logsoftmax_kernel<<<N_NODES / 16, 256, 0, stream>>>(hin, W_out, b_out, out);
}

// Round 4
// 660.463 us; speedup vs baseline: 2.6366x; 1.0956x over previous
//
#include <hip/hip_runtime.h>

#define N_NODES 100000
#define E_EDGES 1600000
#define F_IN    128
#define H_DIM   64
#define C_OUT   16
#define L_LAYERS 3
#define NTOT    (E_EDGES + N_NODES)
#define MAXD    512   // LDS-staged degree cap; fallback recomputes

// ---------------- edge-index dtype detection + conversion ----------------
__global__ void detect64_kernel(const unsigned int* __restrict__ e, int* flag) {
    __shared__ int s_any;
    if (threadIdx.x == 0) s_any = 0;
    __syncthreads();
    int any = 0;
    for (int i = threadIdx.x; i < 2048; i += 256)
        if (e[2 * i + 1] != 0u) any = 1;
    if (any) atomicOr(&s_any, 1);
    __syncthreads();
    if (threadIdx.x == 0) *flag = s_any ? 0 : 1;
}

__global__ void convert_edges_kernel(const void* __restrict__ eidx,
                                     int* __restrict__ e32, const int* __restrict__ flag) {
    int i = blockIdx.x * 256 + threadIdx.x;
    if (i >= 2 * E_EDGES) return;
    int v;
    if (*flag) v = (int)((const long long*)eidx)[i];
    else       v = ((const int*)eidx)[i];
    e32[i] = v;
}

// ---------------- CSR build: deg -> 3-phase scan -> scatter ----------------
__global__ void init_deg_kernel(int* __restrict__ deg) {
    int i = blockIdx.x * 256 + threadIdx.x;
    if (i < N_NODES) deg[i] = 1;   // self-loop
}

__global__ void hist_kernel(const int* __restrict__ dst, int* __restrict__ deg) {
    int i = blockIdx.x * 256 + threadIdx.x;
    if (i < E_EDGES) atomicAdd(&deg[dst[i]], 1);
}

#define SCAN_ELEMS 1024
#define SCAN_NB    ((N_NODES + SCAN_ELEMS - 1) / SCAN_ELEMS)   // 98

__global__ __launch_bounds__(256) void scan_partial_reduce(
        const int* __restrict__ deg, int* __restrict__ partial) {
    __shared__ int sdata[256];
    int b = blockIdx.x, t = threadIdx.x;
    int base = b * SCAN_ELEMS;
    int s = 0;
    #pragma unroll
    for (int j = 0; j < 4; ++j) {
        int idx = base + t + j * 256;
        if (idx < N_NODES) s += deg[idx];
    }
    sdata[t] = s;
    __syncthreads();
    for (int off = 128; off >= 1; off >>= 1) {
        if (t < off) sdata[t] += sdata[t + off];
        __syncthreads();
    }
    if (t == 0) partial[b] = sdata[0];
}

__global__ __launch_bounds__(128) void scan_partial_scan(
        int* __restrict__ partial, int* __restrict__ row_ptr) {
    __shared__ int sd[128];
    int t = threadIdx.x;
    int v = (t < SCAN_NB) ? partial[t] : 0;
    sd[t] = v;
    __syncthreads();
    for (int off = 1; off < 128; off <<= 1) {
        int u = (t >= off) ? sd[t - off] : 0;
        __syncthreads();
        sd[t] += u;
        __syncthreads();
    }
    if (t < SCAN_NB) partial[t] = sd[t] - v;          // exclusive
    if (t == 127) row_ptr[N_NODES] = sd[127];          // total = E+N
}

__global__ __launch_bounds__(256) void scan_write_kernel(
        const int* __restrict__ deg, const int* __restrict__ partial,
        int* __restrict__ row_ptr, int* __restrict__ cur) {
    __shared__ int sd[256];
    int b = blockIdx.x, t = threadIdx.x;
    int base = b * SCAN_ELEMS + t * 4;
    int d0 = 0, d1 = 0, d2 = 0, d3 = 0;
    if (base + 0 < N_NODES) d0 = deg[base + 0];
    if (base + 1 < N_NODES) d1 = deg[base + 1];
    if (base + 2 < N_NODES) d2 = deg[base + 2];
    if (base + 3 < N_NODES) d3 = deg[base + 3];
    int tsum = d0 + d1 + d2 + d3;
    sd[t] = tsum;
    __syncthreads();
    for (int off = 1; off < 256; off <<= 1) {
        int u = (t >= off) ? sd[t - off] : 0;
        __syncthreads();
        sd[t] += u;
        __syncthreads();
    }
    int running = partial[b] + sd[t] - tsum;
    if (base + 0 < N_NODES) { row_ptr[base + 0] = running; cur[base + 0] = running; running += d0; }
    if (base + 1 < N_NODES) { row_ptr[base + 1] = running; cur[base + 1] = running; running += d1; }
    if (base + 2 < N_NODES) { row_ptr[base + 2] = running; cur[base + 2] = running; running += d2; }
    if (base + 3 < N_NODES) { row_ptr[base + 3] = running; cur[base + 3] = running; running += d3; }
}

__global__ void scatter_kernel(const int* __restrict__ src, const int* __restrict__ dst,
                               int* __restrict__ cur, int* __restrict__ csr_src) {
    int i = blockIdx.x * 256 + threadIdx.x;
    if (i >= NTOT) return;
    int s, d;
    if (i < E_EDGES) { s = src[i]; d = dst[i]; }
    else             { s = d = i - E_EDGES; }
    int pos = atomicAdd(&cur[d], 1);
    csr_src[pos] = s;
}

// ---------------- register-tiled GEMM: C[N x 64] = A[N x K] @ W[K x 64] ------
// 128 rows x 64 cols per block, 256 threads, 8x4 register tile per thread.
// A staged in LDS in K-chunks of 32 (stride 36), W staged whole.
// ACT: apply bias + leaky_relu(0.01).  DOTS: write as_/ad_ row dot-products.
#define GBR 128   // rows per block
#define GKC 32    // K-chunk
#define GSA 36    // sA row stride (floats)

template<int K, bool ACT, bool DOTS>
__global__ __launch_bounds__(256) void gemm_tile_kernel(
        const float* __restrict__ A, const float* __restrict__ W,
        const float* __restrict__ bias,
        const float* __restrict__ asrc, const float* __restrict__ adst,
        float* __restrict__ C, float* __restrict__ as_, float* __restrict__ ad_) {
    __shared__ __align__(16) float sW[K * 64];
    __shared__ __align__(16) float sA[GBR * GSA];
    int t = threadIdx.x;
    int r0 = blockIdx.x * GBR;

    // stage W (whole)
    {
        const float4* W4 = (const float4*)W;
        float4* sW4 = (float4*)sW;
        #pragma unroll
        for (int i = t; i < K * 16; i += 256) sW4[i] = W4[i];
    }

    int wave = t >> 6, lane = t & 63;
    int tr = wave * 4 + (lane >> 4);     // 0..15 ; rows = tr + 16*i
    int c0 = (lane & 15) * 4;            // 0..60

    float acc[8][4];
    #pragma unroll
    for (int i = 0; i < 8; ++i)
        #pragma unroll
        for (int j = 0; j < 4; ++j) acc[i][j] = 0.f;

    for (int kc = 0; kc < K; kc += GKC) {
        __syncthreads();
        // stage A chunk: GBR rows x 32 floats
        #pragma unroll
        for (int it = 0; it < 4; ++it) {
            int idx = it * 256 + t;          // 0..1023
            int r = idx >> 3, f4 = (idx & 7) * 4;
            int gr = r0 + r;
            float4 v = make_float4(0.f, 0.f, 0.f, 0.f);
            if (gr < N_NODES) v = *(const float4*)&A[(size_t)gr * K + kc + f4];
            *(float4*)&sA[r * GSA + f4] = v;
        }
        __syncthreads();
        #pragma unroll
        for (int kk = 0; kk < GKC; kk += 4) {
            float4 w0 = *(const float4*)&sW[(kc + kk + 0) * 64 + c0];
            float4 w1 = *(const float4*)&sW[(kc + kk + 1) * 64 + c0];
            float4 w2 = *(const float4*)&sW[(kc + kk + 2) * 64 + c0];
            float4 w3 = *(const float4*)&sW[(kc + kk + 3) * 64 + c0];
            #pragma unroll
            for (int i = 0; i < 8; ++i) {
                float4 a = *(const float4*)&sA[(tr + 16 * i) * GSA + kk];
                acc[i][0] += a.x * w0.x + a.y * w1.x + a.z * w2.x + a.w * w3.x;
                acc[i][1] += a.x * w0.y + a.y * w1.y + a.z * w2.y + a.w * w3.y;
                acc[i][2] += a.x * w0.z + a.y * w1.z + a.z * w2.z + a.w * w3.z;
                acc[i][3] += a.x * w0.w + a.y * w1.w + a.z * w2.w + a.w * w3.w;
            }
        }
    }

    // epilogue
    float bs[4] = {0.f, 0.f, 0.f, 0.f};
    float av[4], dv[4];
    if (ACT) {
        #pragma unroll
        for (int j = 0; j < 4; ++j) bs[j] = bias[c0 + j];
    }
    if (DOTS) {
        #pragma unroll
        for (int j = 0; j < 4; ++j) { av[j] = asrc[c0 + j]; dv[j] = adst[c0 + j]; }
    }
    #pragma unroll
    for (int i = 0; i < 8; ++i) {
        int grow = r0 + tr + 16 * i;
        if (grow >= N_NODES) continue;
        float4 o;
        float* op = (float*)&o;
        #pragma unroll
        for (int j = 0; j < 4; ++j) {
            float v = acc[i][j];
            if (ACT) { v += bs[j]; v = v > 0.f ? v : 0.01f * v; }
            op[j] = v;
        }
        *(float4*)&C[(size_t)grow * 64 + c0] = o;
        if (DOTS) {
            float ds = acc[i][0] * av[0] + acc[i][1] * av[1] + acc[i][2] * av[2] + acc[i][3] * av[3];
            float dd = acc[i][0] * dv[0] + acc[i][1] * dv[1] + acc[i][2] * dv[2] + acc[i][3] * dv[3];
            #pragma unroll
            for (int off = 1; off < 16; off <<= 1) {
                ds += __shfl_xor(ds, off);
                dd += __shfl_xor(dd, off);
            }
            if ((lane & 15) == 0) { as_[grow] = ds; ad_[grow] = dd; }
        }
    }
}

// ---------------- fused aggregation: softmax + weighted gather + bias + act ----
__global__ __launch_bounds__(256) void agg_kernel(
        const int* __restrict__ row_ptr, const int* __restrict__ csr_src,
        const float* __restrict__ as_, const float* __restrict__ ad_,
        const float* __restrict__ hw, const float* __restrict__ bc,
        float* __restrict__ hout) {
    __shared__ float exbuf[4][MAXD];
    __shared__ int   sbuf[4][MAXD];
    int wave = threadIdx.x >> 6, lane = threadIdx.x & 63;
    int node = blockIdx.x * 4 + wave;
    if (node >= N_NODES) return;
    int rs = row_ptr[node], re = row_ptr[node + 1];
    int deg = re - rs;
    float aD = ad_[node];
    float psum = 0.f;
    for (int i = lane; i < deg; i += 64) {
        int s = csr_src[rs + i];
        float v = as_[s] + aD;
        v = v > 0.f ? v : 0.2f * v;
        float p = __expf(v);
        if (deg <= MAXD) { exbuf[wave][i] = p; sbuf[wave][i] = s; }
        psum += p;
    }
    #pragma unroll
    for (int off = 32; off >= 1; off >>= 1) psum += __shfl_xor(psum, off);
    float inv = 1.f / (psum + 1e-16f);
    float acc = 0.f;
    if (deg <= MAXD) {
        int i = 0;
        for (; i + 4 <= deg; i += 4) {
            int s0 = sbuf[wave][i],     s1 = sbuf[wave][i + 1];
            int s2 = sbuf[wave][i + 2], s3 = sbuf[wave][i + 3];
            float w0 = exbuf[wave][i]     * inv, w1 = exbuf[wave][i + 1] * inv;
            float w2 = exbuf[wave][i + 2] * inv, w3 = exbuf[wave][i + 3] * inv;
            acc += w0 * hw[(size_t)s0 * H_DIM + lane];
            acc += w1 * hw[(size_t)s1 * H_DIM + lane];
            acc += w2 * hw[(size_t)s2 * H_DIM + lane];
            acc += w3 * hw[(size_t)s3 * H_DIM + lane];
        }
        for (; i < deg; ++i)
            acc += exbuf[wave][i] * inv * hw[(size_t)sbuf[wave][i] * H_DIM + lane];
    } else {
        for (int i = 0; i < deg; ++i) {
            int s = csr_src[rs + i];
            float v = as_[s] + aD;
            v = v > 0.f ? v : 0.2f * v;
            acc += __expf(v) * inv * hw[(size_t)s * H_DIM + lane];
        }
    }
    float v = acc + bc[lane];
    hout[(size_t)node * H_DIM + lane] = v > 0.f ? v : 0.01f * v;
}

// ---------------- output GEMM + log_softmax ----------------
__global__ __launch_bounds__(256) void out_logsoftmax_kernel(
        const float* __restrict__ h, const float* __restrict__ W,
        const float* __restrict__ b, float* __restrict__ out) {
    __shared__ float sW[H_DIM * C_OUT];
    __shared__ float sh[16][H_DIM];
    __shared__ float sb[C_OUT];
    int t = threadIdx.x;
    for (int i = t; i < H_DIM * C_OUT; i += 256) sW[i] = W[i];
    if (t < C_OUT) sb[t] = b[t];
    int row0 = blockIdx.x * 16;
    for (int i = t; i < 16 * H_DIM; i += 256) {
        int r = i >> 6, k = i & 63;
        sh[r][k] = h[(row0 + r) * H_DIM + k];
    }
    __syncthreads();
    int r = t >> 4, c = t & 15;
    float acc = sb[c];
    #pragma unroll
    for (int k = 0; k < H_DIM; ++k) acc += sh[r][k] * sW[k * C_OUT + c];
    float m = acc;
    #pragma unroll
    for (int off = 8; off >= 1; off >>= 1) m = fmaxf(m, __shfl_xor(m, off, 16));
    float e = __expf(acc - m);
    float ssum = e;
    #pragma unroll
    for (int off = 8; off >= 1; off >>= 1) ssum += __shfl_xor(ssum, off, 16);
    out[(row0 + r) * C_OUT + c] = acc - m - __logf(ssum);
}

extern "C" void kernel_launch(void* const* d_in, const int* in_sizes, int n_in,
                              void* d_out, int out_size, void* d_ws, size_t ws_size,
                              hipStream_t stream) {
    const float* x     = (const float*)d_in[0];
    const void*  eidx  = d_in[1];
    const float* W_in  = (const float*)d_in[3];
    const float* b_in  = (const float*)d_in[4];
    const float* Wc    = (const float*)d_in[5];
    const float* a_src = (const float*)d_in[6];
    const float* a_dst = (const float*)d_in[7];
    const float* bc    = (const float*)d_in[8];
    const float* W_out = (const float*)d_in[9];
    const float* b_out = (const float*)d_in[10];
    float* out = (float*)d_out;

    // workspace layout
    float* h       = (float*)d_ws;                       // N*64
    float* hw      = h  + (size_t)N_NODES * H_DIM;       // N*64
    float* as_     = hw + (size_t)N_NODES * H_DIM;       // N
    float* ad_     = as_ + N_NODES;                      // N
    int*   e32     = (int*)(ad_ + N_NODES);              // 2E
    int*   deg     = e32 + 2 * E_EDGES;                  // N
    int*   row_ptr = deg + N_NODES;                      // N+1
    int*   cur     = row_ptr + N_NODES + 1;              // N
    int*   csr_src = cur + N_NODES;                      // E+N
    int*   partial = csr_src + NTOT;                     // SCAN_NB
    int*   flag    = partial + SCAN_NB;                  // 1

    detect64_kernel<<<1, 256, 0, stream>>>((const unsigned int*)eidx, flag);
    convert_edges_kernel<<<(2 * E_EDGES + 255) / 256, 256, 0, stream>>>(eidx, e32, flag);
    const int* srcp = e32;
    const int* dstp = e32 + E_EDGES;

    // CSR build (by destination), self-loops included
    init_deg_kernel<<<(N_NODES + 255) / 256, 256, 0, stream>>>(deg);
    hist_kernel<<<(E_EDGES + 255) / 256, 256, 0, stream>>>(dstp, deg);
    scan_partial_reduce<<<SCAN_NB, 256, 0, stream>>>(deg, partial);
    scan_partial_scan<<<1, 128, 0, stream>>>(partial, row_ptr);
    scan_write_kernel<<<SCAN_NB, 256, 0, stream>>>(deg, partial, row_ptr, cur);
    scatter_kernel<<<(NTOT + 255) / 256, 256, 0, stream>>>(srcp, dstp, cur, csr_src);

    int gblocks = (N_NODES + GBR - 1) / GBR;
    gemm_tile_kernel<F_IN, true, false><<<gblocks, 256, 0, stream>>>(
        x, W_in, b_in, nullptr, nullptr, h, nullptr, nullptr);

    float* hin = h;
    float* hx  = hw;
    for (int l = 0; l < L_LAYERS; ++l) {
        gemm_tile_kernel<H_DIM, false, true><<<gblocks, 256, 0, stream>>>(
            hin, Wc + l * H_DIM * H_DIM, nullptr,
            a_src + l * H_DIM, a_dst + l * H_DIM, hx, as_, ad_);
        agg_kernel<<<(N_NODES + 3) / 4, 256, 0, stream>>>(
            row_ptr, csr_src, as_, ad_, hx, bc + l * H_DIM, hin);
    }

    out_logsoftmax_kernel<<<N_NODES / 16, 256, 0, stream>>>(hin, W_out, b_out, out);
}

// Round 5
// 575.936 us; speedup vs baseline: 3.0236x; 1.1468x over previous
//
#include <hip/hip_runtime.h>

#define N_NODES 100000
#define E_EDGES 1600000
#define F_IN    128
#define H_DIM   64
#define C_OUT   16
#define L_LAYERS 3
#define NTOT    (E_EDGES + N_NODES)
#define MAXD    512   // LDS-staged degree cap in agg; fallback recomputes

#define BKN     128                                   // nodes per bucket
#define NBUCK   ((N_NODES + BKN - 1) / BKN)           // 782

// ---------------- edge-index dtype detection ----------------
__global__ void detect64_kernel(const unsigned int* __restrict__ e, int* flag) {
    __shared__ int s_any;
    if (threadIdx.x == 0) s_any = 0;
    __syncthreads();
    int any = 0;
    for (int i = threadIdx.x; i < 2048; i += 256)
        if (e[2 * i + 1] != 0u) any = 1;
    if (any) atomicOr(&s_any, 1);
    __syncthreads();
    if (threadIdx.x == 0) *flag = s_any ? 0 : 1;
}

// ---------------- bucketed CSR build ----------------
// pass A: per-bucket edge histogram (LDS-aggregated)
__global__ __launch_bounds__(256) void bucket_hist_kernel(
        const void* __restrict__ eidx, const int* __restrict__ flag,
        int* __restrict__ ecount) {
    __shared__ int hist[NBUCK];
    for (int i = threadIdx.x; i < NBUCK; i += 256) hist[i] = 0;
    __syncthreads();
    int f64 = *flag;
    int stride = gridDim.x * 256;
    for (int i = blockIdx.x * 256 + threadIdx.x; i < E_EDGES; i += stride) {
        int d = f64 ? (int)((const long long*)eidx)[E_EDGES + i]
                    : ((const int*)eidx)[E_EDGES + i];
        atomicAdd(&hist[d >> 7], 1);
    }
    __syncthreads();
    for (int i = threadIdx.x; i < NBUCK; i += 256)
        if (hist[i]) atomicAdd(&ecount[i], hist[i]);
}

// pass A2: exclusive scan of bucket counts; init padded bucket cursors
__global__ __launch_bounds__(1024) void bucket_scan_kernel(
        const int* __restrict__ ecount, int* __restrict__ pack_base,
        int* __restrict__ bcur) {
    __shared__ int sd[1024];
    int t = threadIdx.x;
    int v = (t < NBUCK) ? ecount[t] : 0;
    sd[t] = v;
    __syncthreads();
    for (int off = 1; off < 1024; off <<= 1) {
        int u = (t >= off) ? sd[t - off] : 0;
        __syncthreads();
        sd[t] += u;
        __syncthreads();
    }
    if (t < NBUCK) {
        int ex = sd[t] - v;
        pack_base[t] = ex;
        bcur[t * 16] = ex;   // 64B-padded cursor per bucket
    }
}

// pass B: scatter edges into per-bucket packed arrays (writes stay dense in L2)
__global__ __launch_bounds__(256) void bucket_scatter_kernel(
        const void* __restrict__ eidx, const int* __restrict__ flag,
        int* __restrict__ bcur, unsigned int* __restrict__ packed) {
    int i = blockIdx.x * 256 + threadIdx.x;
    if (i >= E_EDGES) return;
    int f64 = *flag;
    int s, d;
    if (f64) {
        s = (int)((const long long*)eidx)[i];
        d = (int)((const long long*)eidx)[E_EDGES + i];
    } else {
        s = ((const int*)eidx)[i];
        d = ((const int*)eidx)[E_EDGES + i];
    }
    int b = d >> 7;
    int pos = atomicAdd(&bcur[b * 16], 1);
    packed[pos] = ((unsigned)(d & (BKN - 1)) << 17) | (unsigned)s;  // s < 2^17
}

// pass C: per-bucket CSR finalize — count, scan, row_ptr, self-loops, scatter
__global__ __launch_bounds__(256) void csr_build_kernel(
        const unsigned int* __restrict__ packed, const int* __restrict__ pack_base,
        const int* __restrict__ ecount,
        int* __restrict__ row_ptr, int* __restrict__ csr_src) {
    __shared__ int cnt[BKN], scn[BKN], cur[BKN];
    int b = blockIdx.x, t = threadIdx.x;
    int nbase = b * BKN;
    int nn = min(BKN, N_NODES - nbase);
    int pbase = pack_base[b];
    int ec = ecount[b];
    int cbase = pbase + nbase;           // + one self-loop per preceding node
    if (t < BKN) cnt[t] = (t < nn) ? 1 : 0;   // self-loop seed
    __syncthreads();
    for (int i = t; i < ec; i += 256)
        atomicAdd(&cnt[packed[pbase + i] >> 17], 1);
    __syncthreads();
    int myc = (t < BKN) ? cnt[t] : 0;
    if (t < BKN) scn[t] = myc;
    __syncthreads();
    for (int off = 1; off < BKN; off <<= 1) {
        int u = (t < BKN && t >= off) ? scn[t - off] : 0;
        __syncthreads();
        if (t < BKN) scn[t] += u;
        __syncthreads();
    }
    if (t < nn) {
        int offi = scn[t] - myc;                 // exclusive prefix
        row_ptr[nbase + t] = cbase + offi;
        csr_src[cbase + offi] = nbase + t;       // self-loop first
        cur[t] = offi + 1;
    }
    if (b == NBUCK - 1 && t == 0) row_ptr[N_NODES] = cbase + ec + nn;
    __syncthreads();
    for (int i = t; i < ec; i += 256) {
        unsigned p = packed[pbase + i];
        int dl = p >> 17, s = (int)(p & 0x1FFFFu);
        int pos = atomicAdd(&cur[dl], 1);
        csr_src[cbase + pos] = s;
    }
}

// ---------------- register-tiled GEMM: C[N x 64] = A[N x K] @ W[K x 64] ------
#define GBR 128   // rows per block
#define GKC 32    // K-chunk
#define GSA 36    // sA row stride (floats)

template<int K, bool ACT, bool DOTS>
__global__ __launch_bounds__(256) void gemm_tile_kernel(
        const float* __restrict__ A, const float* __restrict__ W,
        const float* __restrict__ bias,
        const float* __restrict__ asrc, const float* __restrict__ adst,
        float* __restrict__ C, float* __restrict__ as_, float* __restrict__ ad_) {
    __shared__ __align__(16) float sW[K * 64];
    __shared__ __align__(16) float sA[GBR * GSA];
    int t = threadIdx.x;
    int r0 = blockIdx.x * GBR;

    {
        const float4* W4 = (const float4*)W;
        float4* sW4 = (float4*)sW;
        #pragma unroll
        for (int i = t; i < K * 16; i += 256) sW4[i] = W4[i];
    }

    int wave = t >> 6, lane = t & 63;
    int tr = wave * 4 + (lane >> 4);
    int c0 = (lane & 15) * 4;

    float acc[8][4];
    #pragma unroll
    for (int i = 0; i < 8; ++i)
        #pragma unroll
        for (int j = 0; j < 4; ++j) acc[i][j] = 0.f;

    for (int kc = 0; kc < K; kc += GKC) {
        __syncthreads();
        #pragma unroll
        for (int it = 0; it < 4; ++it) {
            int idx = it * 256 + t;
            int r = idx >> 3, f4 = (idx & 7) * 4;
            int gr = r0 + r;
            float4 v = make_float4(0.f, 0.f, 0.f, 0.f);
            if (gr < N_NODES) v = *(const float4*)&A[(size_t)gr * K + kc + f4];
            *(float4*)&sA[r * GSA + f4] = v;
        }
        __syncthreads();
        #pragma unroll
        for (int kk = 0; kk < GKC; kk += 4) {
            float4 w0 = *(const float4*)&sW[(kc + kk + 0) * 64 + c0];
            float4 w1 = *(const float4*)&sW[(kc + kk + 1) * 64 + c0];
            float4 w2 = *(const float4*)&sW[(kc + kk + 2) * 64 + c0];
            float4 w3 = *(const float4*)&sW[(kc + kk + 3) * 64 + c0];
            #pragma unroll
            for (int i = 0; i < 8; ++i) {
                float4 a = *(const float4*)&sA[(tr + 16 * i) * GSA + kk];
                acc[i][0] += a.x * w0.x + a.y * w1.x + a.z * w2.x + a.w * w3.x;
                acc[i][1] += a.x * w0.y + a.y * w1.y + a.z * w2.y + a.w * w3.y;
                acc[i][2] += a.x * w0.z + a.y * w1.z + a.z * w2.z + a.w * w3.z;
                acc[i][3] += a.x * w0.w + a.y * w1.w + a.z * w2.w + a.w * w3.w;
            }
        }
    }

    float bs[4] = {0.f, 0.f, 0.f, 0.f};
    float av[4], dv[4];
    if (ACT) {
        #pragma unroll
        for (int j = 0; j < 4; ++j) bs[j] = bias[c0 + j];
    }
    if (DOTS) {
        #pragma unroll
        for (int j = 0; j < 4; ++j) { av[j] = asrc[c0 + j]; dv[j] = adst[c0 + j]; }
    }
    #pragma unroll
    for (int i = 0; i < 8; ++i) {
        int grow = r0 + tr + 16 * i;
        if (grow >= N_NODES) continue;
        float4 o;
        float* op = (float*)&o;
        #pragma unroll
        for (int j = 0; j < 4; ++j) {
            float v = acc[i][j];
            if (ACT) { v += bs[j]; v = v > 0.f ? v : 0.01f * v; }
            op[j] = v;
        }
        *(float4*)&C[(size_t)grow * 64 + c0] = o;
        if (DOTS) {
            float ds = acc[i][0] * av[0] + acc[i][1] * av[1] + acc[i][2] * av[2] + acc[i][3] * av[3];
            float dd = acc[i][0] * dv[0] + acc[i][1] * dv[1] + acc[i][2] * dv[2] + acc[i][3] * dv[3];
            #pragma unroll
            for (int off = 1; off < 16; off <<= 1) {
                ds += __shfl_xor(ds, off);
                dd += __shfl_xor(dd, off);
            }
            if ((lane & 15) == 0) { as_[grow] = ds; ad_[grow] = dd; }
        }
    }
}

// ---------------- fused aggregation: softmax + weighted gather + bias + act ----
__global__ __launch_bounds__(256) void agg_kernel(
        const int* __restrict__ row_ptr, const int* __restrict__ csr_src,
        const float* __restrict__ as_, const float* __restrict__ ad_,
        const float* __restrict__ hw, const float* __restrict__ bc,
        float* __restrict__ hout) {
    __shared__ float exbuf[4][MAXD];
    __shared__ int   sbuf[4][MAXD];
    int wave = threadIdx.x >> 6, lane = threadIdx.x & 63;
    int node = blockIdx.x * 4 + wave;
    if (node >= N_NODES) return;
    int rs = row_ptr[node], re = row_ptr[node + 1];
    int deg = re - rs;
    float aD = ad_[node];
    float psum = 0.f;
    for (int i = lane; i < deg; i += 64) {
        int s = csr_src[rs + i];
        float v = as_[s] + aD;
        v = v > 0.f ? v : 0.2f * v;
        float p = __expf(v);
        if (deg <= MAXD) { exbuf[wave][i] = p; sbuf[wave][i] = s; }
        psum += p;
    }
    #pragma unroll
    for (int off = 32; off >= 1; off >>= 1) psum += __shfl_xor(psum, off);
    float inv = 1.f / (psum + 1e-16f);
    float acc = 0.f;
    if (deg <= MAXD) {
        int i = 0;
        for (; i + 4 <= deg; i += 4) {
            int s0 = sbuf[wave][i],     s1 = sbuf[wave][i + 1];
            int s2 = sbuf[wave][i + 2], s3 = sbuf[wave][i + 3];
            float w0 = exbuf[wave][i]     * inv, w1 = exbuf[wave][i + 1] * inv;
            float w2 = exbuf[wave][i + 2] * inv, w3 = exbuf[wave][i + 3] * inv;
            acc += w0 * hw[(size_t)s0 * H_DIM + lane];
            acc += w1 * hw[(size_t)s1 * H_DIM + lane];
            acc += w2 * hw[(size_t)s2 * H_DIM + lane];
            acc += w3 * hw[(size_t)s3 * H_DIM + lane];
        }
        for (; i < deg; ++i)
            acc += exbuf[wave][i] * inv * hw[(size_t)sbuf[wave][i] * H_DIM + lane];
    } else {
        for (int i = 0; i < deg; ++i) {
            int s = csr_src[rs + i];
            float v = as_[s] + aD;
            v = v > 0.f ? v : 0.2f * v;
            acc += __expf(v) * inv * hw[(size_t)s * H_DIM + lane];
        }
    }
    float v = acc + bc[lane];
    hout[(size_t)node * H_DIM + lane] = v > 0.f ? v : 0.01f * v;
}

// ---------------- output GEMM + log_softmax ----------------
__global__ __launch_bounds__(256) void out_logsoftmax_kernel(
        const float* __restrict__ h, const float* __restrict__ W,
        const float* __restrict__ b, float* __restrict__ out) {
    __shared__ float sW[H_DIM * C_OUT];
    __shared__ float sh[16][H_DIM];
    __shared__ float sb[C_OUT];
    int t = threadIdx.x;
    for (int i = t; i < H_DIM * C_OUT; i += 256) sW[i] = W[i];
    if (t < C_OUT) sb[t] = b[t];
    int row0 = blockIdx.x * 16;
    for (int i = t; i < 16 * H_DIM; i += 256) {
        int r = i >> 6, k = i & 63;
        sh[r][k] = h[(row0 + r) * H_DIM + k];
    }
    __syncthreads();
    int r = t >> 4, c = t & 15;
    float acc = sb[c];
    #pragma unroll
    for (int k = 0; k < H_DIM; ++k) acc += sh[r][k] * sW[k * C_OUT + c];
    float m = acc;
    #pragma unroll
    for (int off = 8; off >= 1; off >>= 1) m = fmaxf(m, __shfl_xor(m, off, 16));
    float e = __expf(acc - m);
    float ssum = e;
    #pragma unroll
    for (int off = 8; off >= 1; off >>= 1) ssum += __shfl_xor(ssum, off, 16);
    out[(row0 + r) * C_OUT + c] = acc - m - __logf(ssum);
}

extern "C" void kernel_launch(void* const* d_in, const int* in_sizes, int n_in,
                              void* d_out, int out_size, void* d_ws, size_t ws_size,
                              hipStream_t stream) {
    const float* x     = (const float*)d_in[0];
    const void*  eidx  = d_in[1];
    const float* W_in  = (const float*)d_in[3];
    const float* b_in  = (const float*)d_in[4];
    const float* Wc    = (const float*)d_in[5];
    const float* a_src = (const float*)d_in[6];
    const float* a_dst = (const float*)d_in[7];
    const float* bc    = (const float*)d_in[8];
    const float* W_out = (const float*)d_in[9];
    const float* b_out = (const float*)d_in[10];
    float* out = (float*)d_out;

    // workspace layout
    float* h        = (float*)d_ws;                        // N*64
    float* hw       = h  + (size_t)N_NODES * H_DIM;        // N*64
    float* as_      = hw + (size_t)N_NODES * H_DIM;        // N
    float* ad_      = as_ + N_NODES;                       // N
    int*   row_ptr  = (int*)(ad_ + N_NODES);               // N+1
    int*   csr_src  = row_ptr + N_NODES + 1;               // E+N
    unsigned int* packed = (unsigned int*)(csr_src + NTOT);// E
    int*   ecount   = (int*)(packed + E_EDGES);            // NBUCK
    int*   pack_base= ecount + NBUCK;                      // NBUCK
    int*   bcur     = pack_base + NBUCK;                   // NBUCK*16
    int*   flag     = bcur + NBUCK * 16;                   // 1

    detect64_kernel<<<1, 256, 0, stream>>>((const unsigned int*)eidx, flag);
    hipMemsetAsync(ecount, 0, NBUCK * sizeof(int), stream);
    bucket_hist_kernel<<<256, 256, 0, stream>>>(eidx, flag, ecount);
    bucket_scan_kernel<<<1, 1024, 0, stream>>>(ecount, pack_base, bcur);
    bucket_scatter_kernel<<<(E_EDGES + 255) / 256, 256, 0, stream>>>(eidx, flag, bcur, packed);
    csr_build_kernel<<<NBUCK, 256, 0, stream>>>(packed, pack_base, ecount, row_ptr, csr_src);

    int gblocks = (N_NODES + GBR - 1) / GBR;
    gemm_tile_kernel<F_IN, true, false><<<gblocks, 256, 0, stream>>>(
        x, W_in, b_in, nullptr, nullptr, h, nullptr, nullptr);

    float* hin = h;
    float* hx  = hw;
    for (int l = 0; l < L_LAYERS; ++l) {
        gemm_tile_kernel<H_DIM, false, true><<<gblocks, 256, 0, stream>>>(
            hin, Wc + l * H_DIM * H_DIM, nullptr,
            a_src + l * H_DIM, a_dst + l * H_DIM, hx, as_, ad_);
        agg_kernel<<<(N_NODES + 3) / 4, 256, 0, stream>>>(
            row_ptr, csr_src, as_, ad_, hx, bc + l * H_DIM, hin);
    }

    out_logsoftmax_kernel<<<N_NODES / 16, 256, 0, stream>>>(hin, W_out, b_out, out);
}

// Round 6
// 495.147 us; speedup vs baseline: 3.5169x; 1.1632x over previous
//
#include <hip/hip_runtime.h>

#define N_NODES 100000
#define E_EDGES 1600000
#define F_IN    128
#define H_DIM   64
#define C_OUT   16
#define L_LAYERS 3
#define NTOT    (E_EDGES + N_NODES)
#define MAXD    512   // LDS-staged degree cap in agg; fallback recomputes

#define BKN2    512                                   // nodes per bucket
#define NB2     ((N_NODES + BKN2 - 1) / BKN2)         // 196
#define BCAP    9216                                  // per-bucket capacity (E[8192]+11sigma)
#define CH      8192                                  // edges per scatter block
#define PB      ((E_EDGES + CH - 1) / CH)             // 196

// ---------------- edge-index dtype detection ----------------
__global__ void detect64_kernel(const unsigned int* __restrict__ e, int* flag) {
    __shared__ int s_any;
    if (threadIdx.x == 0) s_any = 0;
    __syncthreads();
    int any = 0;
    for (int i = threadIdx.x; i < 2048; i += 256)
        if (e[2 * i + 1] != 0u) any = 1;
    if (any) atomicOr(&s_any, 1);
    __syncthreads();
    if (threadIdx.x == 0) *flag = s_any ? 0 : 1;
}

// ---------------- pass B: block-local bucket sort + dense scatter ----------------
// Each block: 8192 edges -> LDS histogram over 196 buckets -> reserve global
// space (1 atomic per bucket per block) -> LDS-sort -> contiguous copy-out.
__global__ __launch_bounds__(256) void bucket_scatter2(
        const void* __restrict__ eidx, const int* __restrict__ flag,
        int* __restrict__ bcur, unsigned int* __restrict__ packed) {
    __shared__ int cnt[NB2], basel[NB2], curl[NB2], gbase[NB2];
    __shared__ int sd[256];
    __shared__ unsigned int stage[CH];
    __shared__ unsigned char bkt[CH];
    int t = threadIdx.x;
    int b0 = blockIdx.x * CH;
    int ne = min(CH, E_EDGES - b0);
    for (int i = t; i < NB2; i += 256) cnt[i] = 0;
    __syncthreads();

    int f64 = *flag;
    int es[CH / 256], ed[CH / 256];
    #pragma unroll
    for (int j = 0; j < CH / 256; ++j) {
        int idx = b0 + j * 256 + t;
        if (idx < E_EDGES) {
            if (f64) {
                es[j] = (int)((const long long*)eidx)[idx];
                ed[j] = (int)((const long long*)eidx)[E_EDGES + idx];
            } else {
                es[j] = ((const int*)eidx)[idx];
                ed[j] = ((const int*)eidx)[E_EDGES + idx];
            }
            atomicAdd(&cnt[ed[j] >> 9], 1);
        } else { es[j] = -1; }
    }
    __syncthreads();
    // scan bucket counts (256-wide, NB2 live)
    int v = (t < NB2) ? cnt[t] : 0;
    sd[t] = v;
    __syncthreads();
    for (int off = 1; off < 256; off <<= 1) {
        int u = (t >= off) ? sd[t - off] : 0;
        __syncthreads();
        sd[t] += u;
        __syncthreads();
    }
    if (t < NB2) {
        basel[t] = sd[t] - v;
        curl[t] = 0;
        gbase[t] = atomicAdd(&bcur[t], v);   // reserve global run
    }
    __syncthreads();
    // place into LDS-sorted stage
    #pragma unroll
    for (int j = 0; j < CH / 256; ++j) {
        if (es[j] >= 0) {
            int b = ed[j] >> 9;
            int r = atomicAdd(&curl[b], 1);
            int pos = basel[b] + r;
            stage[pos] = ((unsigned)(ed[j] & (BKN2 - 1)) << 17) | (unsigned)es[j];
            bkt[pos] = (unsigned char)b;
        }
    }
    __syncthreads();
    // contiguous copy-out per bucket run
    for (int i = t; i < ne; i += 256) {
        int b = bkt[i];
        packed[(size_t)b * BCAP + gbase[b] + (i - basel[b])] = stage[i];
    }
}

// ---------------- pass B2: exclusive scan of final bucket counts ----------------
__global__ __launch_bounds__(256) void bucket_scan2(
        const int* __restrict__ bcur, int* __restrict__ ebase) {
    __shared__ int sd[256];
    int t = threadIdx.x;
    int v = (t < NB2) ? bcur[t] : 0;
    sd[t] = v;
    __syncthreads();
    for (int off = 1; off < 256; off <<= 1) {
        int u = (t >= off) ? sd[t - off] : 0;
        __syncthreads();
        sd[t] += u;
        __syncthreads();
    }
    if (t < NB2) ebase[t] = sd[t] - v;
}

// ---------------- pass C: per-bucket CSR finalize ----------------
__global__ __launch_bounds__(256) void csr_build2(
        const unsigned int* __restrict__ packed, const int* __restrict__ bcur,
        const int* __restrict__ ebase,
        int* __restrict__ row_ptr, int* __restrict__ csr_src) {
    __shared__ int cnt[BKN2], scn[BKN2], cur[BKN2];
    int b = blockIdx.x, t = threadIdx.x;
    int nbase = b * BKN2;
    int nn = min(BKN2, N_NODES - nbase);
    int ec = bcur[b];
    size_t pbase = (size_t)b * BCAP;
    int cbase = ebase[b] + nbase;        // + one self-loop per preceding node
    cnt[t] = (t < nn) ? 1 : 0;
    cnt[t + 256] = (t + 256 < nn) ? 1 : 0;
    __syncthreads();
    for (int i = t; i < ec; i += 256)
        atomicAdd(&cnt[packed[pbase + i] >> 17], 1);
    __syncthreads();
    scn[t] = cnt[t];
    scn[t + 256] = cnt[t + 256];
    __syncthreads();
    for (int off = 1; off < BKN2; off <<= 1) {
        int u0 = (t >= off) ? scn[t - off] : 0;
        int u1 = (t + 256 >= off) ? scn[t + 256 - off] : 0;
        __syncthreads();
        scn[t] += u0;
        scn[t + 256] += u1;
        __syncthreads();
    }
    #pragma unroll
    for (int q = 0; q < 2; ++q) {
        int idx = t + q * 256;
        if (idx < nn) {
            int offi = scn[idx] - cnt[idx];
            row_ptr[nbase + idx] = cbase + offi;
            csr_src[cbase + offi] = nbase + idx;   // self-loop first
            cur[idx] = offi + 1;
        }
    }
    if (b == NB2 - 1 && t == 0) row_ptr[N_NODES] = cbase + ec + nn;
    __syncthreads();
    for (int i = t; i < ec; i += 256) {
        unsigned p = packed[pbase + i];
        int dl = p >> 17, s = (int)(p & 0x1FFFFu);
        int pos = atomicAdd(&cur[dl], 1);
        csr_src[cbase + pos] = s;
    }
}

// ---------------- streaming register-tiled GEMM (no LDS, no barriers) --------
// C[N x 64] = A[N x K] @ W[K x 64]; 128 rows/block, 8x4 regs/thread.
// Each row is consumed by exactly one 16-lane group (broadcast reads, L1 reuse);
// W is block-shared -> L2-resident.
#define GBR 128

template<int K, bool ACT, bool DOTS>
__global__ __launch_bounds__(256) void gemm_tile_kernel(
        const float* __restrict__ A, const float* __restrict__ W,
        const float* __restrict__ bias,
        const float* __restrict__ asrc, const float* __restrict__ adst,
        float* __restrict__ C, float* __restrict__ as_, float* __restrict__ ad_) {
    int t = threadIdx.x;
    int r0 = blockIdx.x * GBR;
    int wave = t >> 6, lane = t & 63;
    int tr = wave * 4 + (lane >> 4);
    int c0 = (lane & 15) * 4;
    int wcol = lane & 15;
    const float4* W4 = (const float4*)W;

    size_t rowoff[8];
    bool valid[8];
    #pragma unroll
    for (int i = 0; i < 8; ++i) {
        int g = r0 + tr + 16 * i;
        valid[i] = g < N_NODES;
        rowoff[i] = (size_t)(valid[i] ? g : (N_NODES - 1)) * K;
    }

    float acc[8][4];
    #pragma unroll
    for (int i = 0; i < 8; ++i)
        #pragma unroll
        for (int j = 0; j < 4; ++j) acc[i][j] = 0.f;

    #pragma unroll 2
    for (int kk = 0; kk < K; kk += 4) {
        float4 w0 = W4[(kk + 0) * 16 + wcol];
        float4 w1 = W4[(kk + 1) * 16 + wcol];
        float4 w2 = W4[(kk + 2) * 16 + wcol];
        float4 w3 = W4[(kk + 3) * 16 + wcol];
        #pragma unroll
        for (int i = 0; i < 8; ++i) {
            float4 a = *(const float4*)&A[rowoff[i] + kk];
            acc[i][0] += a.x * w0.x + a.y * w1.x + a.z * w2.x + a.w * w3.x;
            acc[i][1] += a.x * w0.y + a.y * w1.y + a.z * w2.y + a.w * w3.y;
            acc[i][2] += a.x * w0.z + a.y * w1.z + a.z * w2.z + a.w * w3.z;
            acc[i][3] += a.x * w0.w + a.y * w1.w + a.z * w2.w + a.w * w3.w;
        }
    }

    float bs[4] = {0.f, 0.f, 0.f, 0.f};
    float av[4], dv[4];
    if (ACT) {
        #pragma unroll
        for (int j = 0; j < 4; ++j) bs[j] = bias[c0 + j];
    }
    if (DOTS) {
        #pragma unroll
        for (int j = 0; j < 4; ++j) { av[j] = asrc[c0 + j]; dv[j] = adst[c0 + j]; }
    }
    #pragma unroll
    for (int i = 0; i < 8; ++i) {
        if (!valid[i]) continue;
        int grow = r0 + tr + 16 * i;
        float4 o;
        float* op = (float*)&o;
        #pragma unroll
        for (int j = 0; j < 4; ++j) {
            float v = acc[i][j];
            if (ACT) { v += bs[j]; v = v > 0.f ? v : 0.01f * v; }
            op[j] = v;
        }
        *(float4*)&C[(size_t)grow * 64 + c0] = o;
        if (DOTS) {
            float ds = acc[i][0] * av[0] + acc[i][1] * av[1] + acc[i][2] * av[2] + acc[i][3] * av[3];
            float dd = acc[i][0] * dv[0] + acc[i][1] * dv[1] + acc[i][2] * dv[2] + acc[i][3] * dv[3];
            #pragma unroll
            for (int off = 1; off < 16; off <<= 1) {
                ds += __shfl_xor(ds, off);
                dd += __shfl_xor(dd, off);
            }
            if ((lane & 15) == 0) { as_[grow] = ds; ad_[grow] = dd; }
        }
    }
}

// ---------------- fused aggregation: softmax + weighted gather + bias + act ----
__global__ __launch_bounds__(256) void agg_kernel(
        const int* __restrict__ row_ptr, const int* __restrict__ csr_src,
        const float* __restrict__ as_, const float* __restrict__ ad_,
        const float* __restrict__ hw, const float* __restrict__ bc,
        float* __restrict__ hout) {
    __shared__ float exbuf[4][MAXD];
    __shared__ int   sbuf[4][MAXD];
    int wave = threadIdx.x >> 6, lane = threadIdx.x & 63;
    int node = blockIdx.x * 4 + wave;
    if (node >= N_NODES) return;
    int rs = row_ptr[node], re = row_ptr[node + 1];
    int deg = re - rs;
    float aD = ad_[node];
    float psum = 0.f;
    for (int i = lane; i < deg; i += 64) {
        int s = csr_src[rs + i];
        float v = as_[s] + aD;
        v = v > 0.f ? v : 0.2f * v;
        float p = __expf(v);
        if (deg <= MAXD) { exbuf[wave][i] = p; sbuf[wave][i] = s; }
        psum += p;
    }
    #pragma unroll
    for (int off = 32; off >= 1; off >>= 1) psum += __shfl_xor(psum, off);
    float inv = 1.f / (psum + 1e-16f);
    float acc = 0.f;
    if (deg <= MAXD) {
        int i = 0;
        for (; i + 4 <= deg; i += 4) {
            int s0 = sbuf[wave][i],     s1 = sbuf[wave][i + 1];
            int s2 = sbuf[wave][i + 2], s3 = sbuf[wave][i + 3];
            float w0 = exbuf[wave][i]     * inv, w1 = exbuf[wave][i + 1] * inv;
            float w2 = exbuf[wave][i + 2] * inv, w3 = exbuf[wave][i + 3] * inv;
            acc += w0 * hw[(size_t)s0 * H_DIM + lane];
            acc += w1 * hw[(size_t)s1 * H_DIM + lane];
            acc += w2 * hw[(size_t)s2 * H_DIM + lane];
            acc += w3 * hw[(size_t)s3 * H_DIM + lane];
        }
        for (; i < deg; ++i)
            acc += exbuf[wave][i] * inv * hw[(size_t)sbuf[wave][i] * H_DIM + lane];
    } else {
        for (int i = 0; i < deg; ++i) {
            int s = csr_src[rs + i];
            float v = as_[s] + aD;
            v = v > 0.f ? v : 0.2f * v;
            acc += __expf(v) * inv * hw[(size_t)s * H_DIM + lane];
        }
    }
    float v = acc + bc[lane];
    hout[(size_t)node * H_DIM + lane] = v > 0.f ? v : 0.01f * v;
}

// ---------------- output GEMM + log_softmax ----------------
__global__ __launch_bounds__(256) void out_logsoftmax_kernel(
        const float* __restrict__ h, const float* __restrict__ W,
        const float* __restrict__ b, float* __restrict__ out) {
    __shared__ float sW[H_DIM * C_OUT];
    __shared__ float sh[16][H_DIM];
    __shared__ float sb[C_OUT];
    int t = threadIdx.x;
    for (int i = t; i < H_DIM * C_OUT; i += 256) sW[i] = W[i];
    if (t < C_OUT) sb[t] = b[t];
    int row0 = blockIdx.x * 16;
    for (int i = t; i < 16 * H_DIM; i += 256) {
        int r = i >> 6, k = i & 63;
        sh[r][k] = h[(row0 + r) * H_DIM + k];
    }
    __syncthreads();
    int r = t >> 4, c = t & 15;
    float acc = sb[c];
    #pragma unroll
    for (int k = 0; k < H_DIM; ++k) acc += sh[r][k] * sW[k * C_OUT + c];
    float m = acc;
    #pragma unroll
    for (int off = 8; off >= 1; off >>= 1) m = fmaxf(m, __shfl_xor(m, off, 16));
    float e = __expf(acc - m);
    float ssum = e;
    #pragma unroll
    for (int off = 8; off >= 1; off >>= 1) ssum += __shfl_xor(ssum, off, 16);
    out[(row0 + r) * C_OUT + c] = acc - m - __logf(ssum);
}

extern "C" void kernel_launch(void* const* d_in, const int* in_sizes, int n_in,
                              void* d_out, int out_size, void* d_ws, size_t ws_size,
                              hipStream_t stream) {
    const float* x     = (const float*)d_in[0];
    const void*  eidx  = d_in[1];
    const float* W_in  = (const float*)d_in[3];
    const float* b_in  = (const float*)d_in[4];
    const float* Wc    = (const float*)d_in[5];
    const float* a_src = (const float*)d_in[6];
    const float* a_dst = (const float*)d_in[7];
    const float* bc    = (const float*)d_in[8];
    const float* W_out = (const float*)d_in[9];
    const float* b_out = (const float*)d_in[10];
    float* out = (float*)d_out;

    // workspace layout
    float* h        = (float*)d_ws;                        // N*64
    float* hw       = h  + (size_t)N_NODES * H_DIM;        // N*64
    float* as_      = hw + (size_t)N_NODES * H_DIM;        // N
    float* ad_      = as_ + N_NODES;                       // N
    int*   row_ptr  = (int*)(ad_ + N_NODES);               // N+1
    int*   csr_src  = row_ptr + N_NODES + 1;               // E+N
    unsigned int* packed = (unsigned int*)(csr_src + NTOT);// NB2*BCAP
    int*   bcur     = (int*)(packed + (size_t)NB2 * BCAP); // NB2
    int*   ebase    = bcur + NB2;                          // NB2
    int*   flag     = ebase + NB2;                         // 1

    detect64_kernel<<<1, 256, 0, stream>>>((const unsigned int*)eidx, flag);
    hipMemsetAsync(bcur, 0, NB2 * sizeof(int), stream);
    bucket_scatter2<<<PB, 256, 0, stream>>>(eidx, flag, bcur, packed);
    bucket_scan2<<<1, 256, 0, stream>>>(bcur, ebase);
    csr_build2<<<NB2, 256, 0, stream>>>(packed, bcur, ebase, row_ptr, csr_src);

    int gblocks = (N_NODES + GBR - 1) / GBR;
    gemm_tile_kernel<F_IN, true, false><<<gblocks, 256, 0, stream>>>(
        x, W_in, b_in, nullptr, nullptr, h, nullptr, nullptr);

    float* hin = h;
    float* hx  = hw;
    for (int l = 0; l < L_LAYERS; ++l) {
        gemm_tile_kernel<H_DIM, false, true><<<gblocks, 256, 0, stream>>>(
            hin, Wc + l * H_DIM * H_DIM, nullptr,
            a_src + l * H_DIM, a_dst + l * H_DIM, hx, as_, ad_);
        agg_kernel<<<(N_NODES + 3) / 4, 256, 0, stream>>>(
            row_ptr, csr_src, as_, ad_, hx, bc + l * H_DIM, hin);
    }

    out_logsoftmax_kernel<<<N_NODES / 16, 256, 0, stream>>>(hin, W_out, b_out, out);
}

// Round 7
// 488.440 us; speedup vs baseline: 3.5652x; 1.0137x over previous
//
#include <hip/hip_runtime.h>

#define N_NODES 100000
#define E_EDGES 1600000
#define F_IN    128
#define H_DIM   64
#define C_OUT   16
#define L_LAYERS 3
#define NTOT    (E_EDGES + N_NODES)
#define MAXD    512   // LDS-staged degree cap in agg; fallback recomputes

#define BKN2    512                                   // nodes per bucket
#define NB2     ((N_NODES + BKN2 - 1) / BKN2)         // 196
#define BCAP    9216                                  // per-bucket capacity
#define CH      8192                                  // edges per scatter block
#define PB      ((E_EDGES + CH - 1) / CH)             // 196

// ---------------- edge-index dtype detection ----------------
__global__ void detect64_kernel(const unsigned int* __restrict__ e, int* flag) {
    __shared__ int s_any;
    if (threadIdx.x == 0) s_any = 0;
    __syncthreads();
    int any = 0;
    for (int i = threadIdx.x; i < 2048; i += 256)
        if (e[2 * i + 1] != 0u) any = 1;
    if (any) atomicOr(&s_any, 1);
    __syncthreads();
    if (threadIdx.x == 0) *flag = s_any ? 0 : 1;
}

// ---------------- pass B: block-local bucket sort + dense scatter ----------------
__global__ __launch_bounds__(256) void bucket_scatter2(
        const void* __restrict__ eidx, const int* __restrict__ flag,
        int* __restrict__ bcur, unsigned int* __restrict__ packed) {
    __shared__ int cnt[NB2], basel[NB2], curl[NB2], gbase[NB2];
    __shared__ int sd[256];
    __shared__ unsigned int stage[CH];
    __shared__ unsigned char bkt[CH];
    int t = threadIdx.x;
    int b0 = blockIdx.x * CH;
    int ne = min(CH, E_EDGES - b0);
    for (int i = t; i < NB2; i += 256) cnt[i] = 0;
    __syncthreads();

    int f64 = *flag;
    int es[CH / 256], ed[CH / 256];
    #pragma unroll
    for (int j = 0; j < CH / 256; ++j) {
        int idx = b0 + j * 256 + t;
        if (idx < E_EDGES) {
            if (f64) {
                es[j] = (int)((const long long*)eidx)[idx];
                ed[j] = (int)((const long long*)eidx)[E_EDGES + idx];
            } else {
                es[j] = ((const int*)eidx)[idx];
                ed[j] = ((const int*)eidx)[E_EDGES + idx];
            }
            atomicAdd(&cnt[ed[j] >> 9], 1);
        } else { es[j] = -1; }
    }
    __syncthreads();
    int v = (t < NB2) ? cnt[t] : 0;
    sd[t] = v;
    __syncthreads();
    for (int off = 1; off < 256; off <<= 1) {
        int u = (t >= off) ? sd[t - off] : 0;
        __syncthreads();
        sd[t] += u;
        __syncthreads();
    }
    if (t < NB2) {
        basel[t] = sd[t] - v;
        curl[t] = 0;
        gbase[t] = atomicAdd(&bcur[t], v);
    }
    __syncthreads();
    #pragma unroll
    for (int j = 0; j < CH / 256; ++j) {
        if (es[j] >= 0) {
            int b = ed[j] >> 9;
            int r = atomicAdd(&curl[b], 1);
            int pos = basel[b] + r;
            stage[pos] = ((unsigned)(ed[j] & (BKN2 - 1)) << 17) | (unsigned)es[j];
            bkt[pos] = (unsigned char)b;
        }
    }
    __syncthreads();
    for (int i = t; i < ne; i += 256) {
        int b = bkt[i];
        packed[(size_t)b * BCAP + gbase[b] + (i - basel[b])] = stage[i];
    }
}

// ---------------- pass B2: exclusive scan of final bucket counts ----------------
__global__ __launch_bounds__(256) void bucket_scan2(
        const int* __restrict__ bcur, int* __restrict__ ebase) {
    __shared__ int sd[256];
    int t = threadIdx.x;
    int v = (t < NB2) ? bcur[t] : 0;
    sd[t] = v;
    __syncthreads();
    for (int off = 1; off < 256; off <<= 1) {
        int u = (t >= off) ? sd[t - off] : 0;
        __syncthreads();
        sd[t] += u;
        __syncthreads();
    }
    if (t < NB2) ebase[t] = sd[t] - v;
}

// ---------------- pass C: per-bucket CSR finalize ----------------
__global__ __launch_bounds__(256) void csr_build2(
        const unsigned int* __restrict__ packed, const int* __restrict__ bcur,
        const int* __restrict__ ebase,
        int* __restrict__ row_ptr, int* __restrict__ csr_src) {
    __shared__ int cnt[BKN2], scn[BKN2], cur[BKN2];
    int b = blockIdx.x, t = threadIdx.x;
    int nbase = b * BKN2;
    int nn = min(BKN2, N_NODES - nbase);
    int ec = bcur[b];
    size_t pbase = (size_t)b * BCAP;
    int cbase = ebase[b] + nbase;
    cnt[t] = (t < nn) ? 1 : 0;
    cnt[t + 256] = (t + 256 < nn) ? 1 : 0;
    __syncthreads();
    for (int i = t; i < ec; i += 256)
        atomicAdd(&cnt[packed[pbase + i] >> 17], 1);
    __syncthreads();
    scn[t] = cnt[t];
    scn[t + 256] = cnt[t + 256];
    __syncthreads();
    for (int off = 1; off < BKN2; off <<= 1) {
        int u0 = (t >= off) ? scn[t - off] : 0;
        int u1 = (t + 256 >= off) ? scn[t + 256 - off] : 0;
        __syncthreads();
        scn[t] += u0;
        scn[t + 256] += u1;
        __syncthreads();
    }
    #pragma unroll
    for (int q = 0; q < 2; ++q) {
        int idx = t + q * 256;
        if (idx < nn) {
            int offi = scn[idx] - cnt[idx];
            row_ptr[nbase + idx] = cbase + offi;
            csr_src[cbase + offi] = nbase + idx;   // self-loop first
            cur[idx] = offi + 1;
        }
    }
    if (b == NB2 - 1 && t == 0) row_ptr[N_NODES] = cbase + ec + nn;
    __syncthreads();
    for (int i = t; i < ec; i += 256) {
        unsigned p = packed[pbase + i];
        int dl = p >> 17, s = (int)(p & 0x1FFFFu);
        int pos = atomicAdd(&cur[dl], 1);
        csr_src[cbase + pos] = s;
    }
}

// ---------------- streaming register GEMM (no LDS), high-occupancy ----------
// C[N x 64] = A[N x K] @ W[K x 64]; 32 rows/block, 2 rows x 4 cols per thread.
// 3125 blocks -> 8 resident waves/SIMD for latency hiding.
#define GBR 32

template<int K, bool ACT, bool DOTS>
__global__ __launch_bounds__(256) void gemm_tile_kernel(
        const float* __restrict__ A, const float* __restrict__ W,
        const float* __restrict__ bias,
        const float* __restrict__ asrc, const float* __restrict__ adst,
        float* __restrict__ C, float* __restrict__ as_, float* __restrict__ ad_) {
    int t = threadIdx.x;
    int r0 = blockIdx.x * GBR;
    int wave = t >> 6, lane = t & 63;
    int tr = wave * 4 + (lane >> 4);     // 0..15; rows = tr + 16*i, i=0..1
    int c0 = (lane & 15) * 4;
    int wcol = lane & 15;
    const float4* W4 = (const float4*)W;

    size_t rowoff[2];
    bool valid[2];
    #pragma unroll
    for (int i = 0; i < 2; ++i) {
        int g = r0 + tr + 16 * i;
        valid[i] = g < N_NODES;
        rowoff[i] = (size_t)(valid[i] ? g : (N_NODES - 1)) * K;
    }

    float acc[2][4];
    #pragma unroll
    for (int i = 0; i < 2; ++i)
        #pragma unroll
        for (int j = 0; j < 4; ++j) acc[i][j] = 0.f;

    #pragma unroll 4
    for (int kk = 0; kk < K; kk += 4) {
        float4 w0 = W4[(kk + 0) * 16 + wcol];
        float4 w1 = W4[(kk + 1) * 16 + wcol];
        float4 w2 = W4[(kk + 2) * 16 + wcol];
        float4 w3 = W4[(kk + 3) * 16 + wcol];
        #pragma unroll
        for (int i = 0; i < 2; ++i) {
            float4 a = *(const float4*)&A[rowoff[i] + kk];
            acc[i][0] += a.x * w0.x + a.y * w1.x + a.z * w2.x + a.w * w3.x;
            acc[i][1] += a.x * w0.y + a.y * w1.y + a.z * w2.y + a.w * w3.y;
            acc[i][2] += a.x * w0.z + a.y * w1.z + a.z * w2.z + a.w * w3.z;
            acc[i][3] += a.x * w0.w + a.y * w1.w + a.z * w2.w + a.w * w3.w;
        }
    }

    float bs[4] = {0.f, 0.f, 0.f, 0.f};
    float av[4], dv[4];
    if (ACT) {
        #pragma unroll
        for (int j = 0; j < 4; ++j) bs[j] = bias[c0 + j];
    }
    if (DOTS) {
        #pragma unroll
        for (int j = 0; j < 4; ++j) { av[j] = asrc[c0 + j]; dv[j] = adst[c0 + j]; }
    }
    #pragma unroll
    for (int i = 0; i < 2; ++i) {
        if (!valid[i]) continue;
        int grow = r0 + tr + 16 * i;
        float4 o;
        float* op = (float*)&o;
        #pragma unroll
        for (int j = 0; j < 4; ++j) {
            float v = acc[i][j];
            if (ACT) { v += bs[j]; v = v > 0.f ? v : 0.01f * v; }
            op[j] = v;
        }
        *(float4*)&C[(size_t)grow * 64 + c0] = o;
        if (DOTS) {
            float ds = acc[i][0] * av[0] + acc[i][1] * av[1] + acc[i][2] * av[2] + acc[i][3] * av[3];
            float dd = acc[i][0] * dv[0] + acc[i][1] * dv[1] + acc[i][2] * dv[2] + acc[i][3] * dv[3];
            #pragma unroll
            for (int off = 1; off < 16; off <<= 1) {
                ds += __shfl_xor(ds, off);
                dd += __shfl_xor(dd, off);
            }
            if ((lane & 15) == 0) { as_[grow] = ds; ad_[grow] = dd; }
        }
    }
}

// ---------------- fused aggregation: softmax + weighted gather + bias + act ----
__global__ __launch_bounds__(256) void agg_kernel(
        const int* __restrict__ row_ptr, const int* __restrict__ csr_src,
        const float* __restrict__ as_, const float* __restrict__ ad_,
        const float* __restrict__ hw, const float* __restrict__ bc,
        float* __restrict__ hout) {
    __shared__ float exbuf[4][MAXD];
    __shared__ int   sbuf[4][MAXD];
    int wave = threadIdx.x >> 6, lane = threadIdx.x & 63;
    int node = blockIdx.x * 4 + wave;
    if (node >= N_NODES) return;
    int rs = row_ptr[node], re = row_ptr[node + 1];
    int deg = re - rs;
    float aD = ad_[node];
    float psum = 0.f;
    for (int i = lane; i < deg; i += 64) {
        int s = csr_src[rs + i];
        float v = as_[s] + aD;
        v = v > 0.f ? v : 0.2f * v;
        float p = __expf(v);
        if (deg <= MAXD) { exbuf[wave][i] = p; sbuf[wave][i] = s; }
        psum += p;
    }
    #pragma unroll
    for (int off = 32; off >= 1; off >>= 1) psum += __shfl_xor(psum, off);
    float inv = 1.f / (psum + 1e-16f);
    float acc = 0.f;
    if (deg <= MAXD) {
        int i = 0;
        for (; i + 4 <= deg; i += 4) {
            int s0 = sbuf[wave][i],     s1 = sbuf[wave][i + 1];
            int s2 = sbuf[wave][i + 2], s3 = sbuf[wave][i + 3];
            float w0 = exbuf[wave][i]     * inv, w1 = exbuf[wave][i + 1] * inv;
            float w2 = exbuf[wave][i + 2] * inv, w3 = exbuf[wave][i + 3] * inv;
            acc += w0 * hw[(size_t)s0 * H_DIM + lane];
            acc += w1 * hw[(size_t)s1 * H_DIM + lane];
            acc += w2 * hw[(size_t)s2 * H_DIM + lane];
            acc += w3 * hw[(size_t)s3 * H_DIM + lane];
        }
        for (; i < deg; ++i)
            acc += exbuf[wave][i] * inv * hw[(size_t)sbuf[wave][i] * H_DIM + lane];
    } else {
        for (int i = 0; i < deg; ++i) {
            int s = csr_src[rs + i];
            float v = as_[s] + aD;
            v = v > 0.f ? v : 0.2f * v;
            acc += __expf(v) * inv * hw[(size_t)s * H_DIM + lane];
        }
    }
    float v = acc + bc[lane];
    hout[(size_t)node * H_DIM + lane] = v > 0.f ? v : 0.01f * v;
}

// ---------------- output GEMM + log_softmax ----------------
__global__ __launch_bounds__(256) void out_logsoftmax_kernel(
        const float* __restrict__ h, const float* __restrict__ W,
        const float* __restrict__ b, float* __restrict__ out) {
    __shared__ float sW[H_DIM * C_OUT];
    __shared__ float sh[16][H_DIM];
    __shared__ float sb[C_OUT];
    int t = threadIdx.x;
    for (int i = t; i < H_DIM * C_OUT; i += 256) sW[i] = W[i];
    if (t < C_OUT) sb[t] = b[t];
    int row0 = blockIdx.x * 16;
    for (int i = t; i < 16 * H_DIM; i += 256) {
        int r = i >> 6, k = i & 63;
        sh[r][k] = h[(row0 + r) * H_DIM + k];
    }
    __syncthreads();
    int r = t >> 4, c = t & 15;
    float acc = sb[c];
    #pragma unroll
    for (int k = 0; k < H_DIM; ++k) acc += sh[r][k] * sW[k * C_OUT + c];
    float m = acc;
    #pragma unroll
    for (int off = 8; off >= 1; off >>= 1) m = fmaxf(m, __shfl_xor(m, off, 16));
    float e = __expf(acc - m);
    float ssum = e;
    #pragma unroll
    for (int off = 8; off >= 1; off >>= 1) ssum += __shfl_xor(ssum, off, 16);
    out[(row0 + r) * C_OUT + c] = acc - m - __logf(ssum);
}

extern "C" void kernel_launch(void* const* d_in, const int* in_sizes, int n_in,
                              void* d_out, int out_size, void* d_ws, size_t ws_size,
                              hipStream_t stream) {
    const float* x     = (const float*)d_in[0];
    const void*  eidx  = d_in[1];
    const float* W_in  = (const float*)d_in[3];
    const float* b_in  = (const float*)d_in[4];
    const float* Wc    = (const float*)d_in[5];
    const float* a_src = (const float*)d_in[6];
    const float* a_dst = (const float*)d_in[7];
    const float* bc    = (const float*)d_in[8];
    const float* W_out = (const float*)d_in[9];
    const float* b_out = (const float*)d_in[10];
    float* out = (float*)d_out;

    // workspace layout
    float* h        = (float*)d_ws;                        // N*64
    float* hw       = h  + (size_t)N_NODES * H_DIM;        // N*64
    float* as_      = hw + (size_t)N_NODES * H_DIM;        // N
    float* ad_      = as_ + N_NODES;                       // N
    int*   row_ptr  = (int*)(ad_ + N_NODES);               // N+1
    int*   csr_src  = row_ptr + N_NODES + 1;               // E+N
    unsigned int* packed = (unsigned int*)(csr_src + NTOT);// NB2*BCAP
    int*   bcur     = (int*)(packed + (size_t)NB2 * BCAP); // NB2
    int*   ebase    = bcur + NB2;                          // NB2
    int*   flag     = ebase + NB2;                         // 1

    detect64_kernel<<<1, 256, 0, stream>>>((const unsigned int*)eidx, flag);
    hipMemsetAsync(bcur, 0, NB2 * sizeof(int), stream);
    bucket_scatter2<<<PB, 256, 0, stream>>>(eidx, flag, bcur, packed);
    bucket_scan2<<<1, 256, 0, stream>>>(bcur, ebase);
    csr_build2<<<NB2, 256, 0, stream>>>(packed, bcur, ebase, row_ptr, csr_src);

    int gblocks = (N_NODES + GBR - 1) / GBR;
    gemm_tile_kernel<F_IN, true, false><<<gblocks, 256, 0, stream>>>(
        x, W_in, b_in, nullptr, nullptr, h, nullptr, nullptr);

    float* hin = h;
    float* hx  = hw;
    for (int l = 0; l < L_LAYERS; ++l) {
        gemm_tile_kernel<H_DIM, false, true><<<gblocks, 256, 0, stream>>>(
            hin, Wc + l * H_DIM * H_DIM, nullptr,
            a_src + l * H_DIM, a_dst + l * H_DIM, hx, as_, ad_);
        agg_kernel<<<(N_NODES + 3) / 4, 256, 0, stream>>>(
            row_ptr, csr_src, as_, ad_, hx, bc + l * H_DIM, hin);
    }

    out_logsoftmax_kernel<<<N_NODES / 16, 256, 0, stream>>>(hin, W_out, b_out, out);
}